// Round 3
// baseline (1581.053 us; speedup 1.0000x reference)
//
#include <hip/hip_runtime.h>

#define N_NODES 20000
#define N_EDGES 640000
#define OBS 64
#define HDIM 256
#define MSGD 128
#define ADIM 16
#define NTILES 1250            // N_NODES / 16
#define Q_OFF 0
#define HN_OFF (N_NODES * ADIM)   // 320000

typedef __bf16 bf16x8 __attribute__((ext_vector_type(8)));
typedef float  f32x4  __attribute__((ext_vector_type(4)));

__device__ __forceinline__ unsigned short f2bf(float f) {
    union { float f; unsigned int i; } v; v.f = f;
    unsigned int i = v.i;
    return (unsigned short)((i + 0x7fffu + ((i >> 16) & 1u)) >> 16);
}
__device__ __forceinline__ float bf2f(unsigned short u) {
    union { unsigned int i; float f; } v; v.i = ((unsigned int)u) << 16; return v.f;
}
// 16B vector load of 8 bf16 from LDS/global bf16 buffers
__device__ __forceinline__ bf16x8 ld8(const unsigned short* p) {
    bf16x8 r;
    __builtin_memcpy(&r, __builtin_assume_aligned(p, 16), 16);
    return r;
}
// load 8 consecutive fp32, round to bf16 fragment in registers
__device__ __forceinline__ bf16x8 ldf8(const float* p) {
    const float4* q = (const float4*)__builtin_assume_aligned(p, 16);
    float4 a = q[0], b = q[1];
    union { unsigned short u[8]; bf16x8 v; } r;
    r.u[0] = f2bf(a.x); r.u[1] = f2bf(a.y); r.u[2] = f2bf(a.z); r.u[3] = f2bf(a.w);
    r.u[4] = f2bf(b.x); r.u[5] = f2bf(b.y); r.u[6] = f2bf(b.z); r.u[7] = f2bf(b.w);
    return r.v;
}
__device__ __forceinline__ f32x4 mfma16(bf16x8 a, bf16x8 b, f32x4 c) {
    return __builtin_amdgcn_mfma_f32_16x16x32_bf16(a, b, c, 0, 0, 0);
}
__device__ __forceinline__ float sigmoidf_(float x) { return 1.0f / (1.0f + __expf(-x)); }
__device__ __forceinline__ float tanhf_(float x) { return 2.0f / (1.0f + __expf(-2.0f * x)) - 1.0f; }

// ---------------- ws layout (bytes) ----------------
#define WS_W0T   0u          // 256x64  bf16 : 32768
#define WS_W1T   32768u      // 256x256 bf16 : 131072
#define WS_WMT   163840u     // 128x512 bf16 : 131072
#define WS_WIHT  294912u     // 768x384 bf16 : 589824
#define WS_WHHT  884736u     // 768x256 bf16 : 393216
#define WS_WOT   1277952u    // 16x256  bf16 : 8192
#define WS_X     1286144u    // 20000x256 bf16 : 10240000
#define WS_MNODE 11526144u   // 20000x128 bf16 : 5120000
#define WS_SUMS  16646144u   // 20000x128 f32  : 10240000
#define WS_CNT   26886144u   // 20000 f32      : 80000
// zero region: sums..cnt contiguous = 10320000 B = 645000 float4

__global__ __launch_bounds__(256) void zero_kernel(float4* z) {
    int i = blockIdx.x * 256 + threadIdx.x;
    int np = gridDim.x * 256;
    for (; i < 645000; i += np) z[i] = make_float4(0.f, 0.f, 0.f, 0.f);
}

// transpose fp32 weights into bf16 N-major (K contiguous) layouts
__global__ __launch_bounds__(256) void transpose_weights(
    const float* w0, const float* w1, const float* wm,
    const float* wih, const float* whh, const float* wo,
    unsigned short* w0t, unsigned short* w1t, unsigned short* wmt,
    unsigned short* wiht, unsigned short* whht, unsigned short* wot)
{
    int tid = blockIdx.x * 256 + threadIdx.x;
    int np = gridDim.x * 256;
    for (int i = tid; i < 256 * 64; i += np)  { int n = i / 64,  k = i % 64;  w0t[i]  = f2bf(w0[k * 256 + n]); }
    for (int i = tid; i < 256 * 256; i += np) { int n = i / 256, k = i % 256; w1t[i]  = f2bf(w1[k * 256 + n]); }
    for (int i = tid; i < 128 * 512; i += np) { int n = i / 512, k = i % 512; wmt[i]  = f2bf(wm[k * 128 + n]); }
    for (int i = tid; i < 768 * 384; i += np) { int n = i / 384, k = i % 384; wiht[i] = f2bf(wih[k * 768 + n]); }
    for (int i = tid; i < 768 * 256; i += np) { int n = i / 256, k = i % 256; whht[i] = f2bf(whh[k * 768 + n]); }
    for (int i = tid; i < 16 * 256; i += np)  { int n = i / 256, k = i % 256; wot[i]  = f2bf(wo[k * 16 + n]); }
}

// enc0 -> relu -> enc1 -> relu -> per-node message. One wave = 16 node rows.
__global__ __launch_bounds__(256) void enc_msg_kernel(
    const float* __restrict__ feat, const float* __restrict__ h,
    const unsigned short* __restrict__ w0t, const float* __restrict__ b0,
    const unsigned short* __restrict__ w1t, const float* __restrict__ b1,
    const unsigned short* __restrict__ wmt, const float* __restrict__ mb,
    unsigned short* __restrict__ X, unsigned short* __restrict__ Mnode)
{
    const int wave = threadIdx.x >> 6;
    const int lane = threadIdx.x & 63;
    int tile = blockIdx.x * 4 + wave;
    if (tile >= NTILES) tile = NTILES - 1;   // clamp: duplicate work, barrier-safe
    const int m0 = tile * 16;
    const int lr = lane & 15;        // A-row / B-col / C-col
    const int lq = lane >> 4;        // k-quad (A/B), row-quad (C)

    __shared__ __align__(16) unsigned short lds[4][2][16 * 264];  // per-wave x0/x1 (pad 264)
    unsigned short* x0buf = lds[wave][0];
    unsigned short* x1buf = lds[wave][1];

    // ---- Stage A: X0 = relu(feat @ W0 + b0) -> LDS ----
    for (int t = 0; t < 16; ++t) {
        f32x4 acc = {0.f, 0.f, 0.f, 0.f};
        for (int k0 = 0; k0 < OBS; k0 += 32) {
            bf16x8 a = ldf8(feat + (m0 + lr) * OBS + k0 + lq * 8);
            bf16x8 b = ld8(w0t + (t * 16 + lr) * OBS + k0 + lq * 8);
            acc = mfma16(a, b, acc);
        }
        float bias = b0[t * 16 + lr];
        for (int r = 0; r < 4; ++r) {
            float v = fmaxf(acc[r] + bias, 0.f);
            x0buf[(lq * 4 + r) * 264 + t * 16 + lr] = f2bf(v);
        }
    }
    __syncthreads();
    // ---- Stage B: X = relu(X0 @ W1 + b1) -> LDS + global ----
    for (int t = 0; t < 16; ++t) {
        f32x4 acc = {0.f, 0.f, 0.f, 0.f};
        for (int k0 = 0; k0 < HDIM; k0 += 32) {
            bf16x8 a = ld8(x0buf + lr * 264 + k0 + lq * 8);
            bf16x8 b = ld8(w1t + (t * 16 + lr) * HDIM + k0 + lq * 8);
            acc = mfma16(a, b, acc);
        }
        float bias = b1[t * 16 + lr];
        for (int r = 0; r < 4; ++r) {
            float v = fmaxf(acc[r] + bias, 0.f);
            unsigned short xb = f2bf(v);
            X[(m0 + lq * 4 + r) * HDIM + t * 16 + lr] = xb;
            x1buf[(lq * 4 + r) * 264 + t * 16 + lr] = xb;
        }
    }
    __syncthreads();
    // ---- Stage C: Mnode = X @ Wx + h @ Wh + mb -> global ----
    for (int t = 0; t < 8; ++t) {
        f32x4 acc = {0.f, 0.f, 0.f, 0.f};
        for (int k0 = 0; k0 < HDIM; k0 += 32) {   // X part, from LDS copy
            bf16x8 a = ld8(x1buf + lr * 264 + k0 + lq * 8);
            bf16x8 b = ld8(wmt + (t * 16 + lr) * 512 + k0 + lq * 8);
            acc = mfma16(a, b, acc);
        }
        for (int k0 = 0; k0 < HDIM; k0 += 32) {   // h part, fp32 -> bf16 inline
            bf16x8 a = ldf8(h + (m0 + lr) * HDIM + k0 + lq * 8);
            bf16x8 b = ld8(wmt + (t * 16 + lr) * 512 + 256 + k0 + lq * 8);
            acc = mfma16(a, b, acc);
        }
        float bias = mb[t * 16 + lr];
        for (int r = 0; r < 4; ++r)
            Mnode[(m0 + lq * 4 + r) * MSGD + t * 16 + lr] = f2bf(acc[r] + bias);
    }
}

// scatter-add messages by dst. 32 threads per edge, 4 bf16 each.
__global__ __launch_bounds__(256) void edge_scatter(
    const int* __restrict__ src, const int* __restrict__ dst,
    const unsigned short* __restrict__ Mnode,
    float* __restrict__ sums, float* __restrict__ cnt)
{
    unsigned long long t = (unsigned long long)blockIdx.x * 256 + threadIdx.x;
    int e = (int)(t >> 5);
    if (e >= N_EDGES) return;
    int g = (int)(t & 31);
    int s = src[e], d = dst[e];
    ushort4 m;
    __builtin_memcpy(&m, Mnode + s * MSGD + g * 4, 8);
    float* op = sums + d * MSGD + g * 4;
    atomicAdd(op + 0, bf2f(m.x));
    atomicAdd(op + 1, bf2f(m.y));
    atomicAdd(op + 2, bf2f(m.z));
    atomicAdd(op + 3, bf2f(m.w));
    if (g == 0) atomicAdd(cnt + d, 1.0f);
}

// GRU cell + output head. One wave = 16 node rows.
__global__ __launch_bounds__(256) void gru_out_kernel(
    const float* __restrict__ h, const unsigned short* __restrict__ X,
    const float* __restrict__ sums, const float* __restrict__ cnt,
    const unsigned short* __restrict__ wiht, const unsigned short* __restrict__ whht,
    const float* __restrict__ bih, const float* __restrict__ bhh,
    const unsigned short* __restrict__ wot, const float* __restrict__ ob,
    float* __restrict__ out)
{
    const int wave = threadIdx.x >> 6;
    const int lane = threadIdx.x & 63;
    int tile = blockIdx.x * 4 + wave;
    if (tile >= NTILES) tile = NTILES - 1;   // clamp (barrier-safe)
    const int m0 = tile * 16;
    const int lr = lane & 15;
    const int lq = lane >> 4;

    __shared__ __align__(16) unsigned short lds[4][16 * 264];
    unsigned short* hbuf = lds[wave];

    float cbar = cnt[m0 + lr];
    float invc = 1.0f / fmaxf(cbar, 1.0f);

    for (int t = 0; t < 16; ++t) {
        f32x4 air = {0.f,0.f,0.f,0.f}, aiz = {0.f,0.f,0.f,0.f}, ain = {0.f,0.f,0.f,0.f};
        f32x4 ahr = {0.f,0.f,0.f,0.f}, ahz = {0.f,0.f,0.f,0.f}, ahn = {0.f,0.f,0.f,0.f};
        // u @ Wih, X part (k = 0..255 of u), X already bf16
        for (int k0 = 0; k0 < HDIM; k0 += 32) {
            bf16x8 a = ld8(X + (m0 + lr) * HDIM + k0 + lq * 8);
            bf16x8 br = ld8(wiht + (0 * 256 + t * 16 + lr) * 384 + k0 + lq * 8);
            bf16x8 bz = ld8(wiht + (1 * 256 + t * 16 + lr) * 384 + k0 + lq * 8);
            bf16x8 bn = ld8(wiht + (2 * 256 + t * 16 + lr) * 384 + k0 + lq * 8);
            air = mfma16(a, br, air); aiz = mfma16(a, bz, aiz); ain = mfma16(a, bn, ain);
        }
        // u @ Wih, c part (k = 256..383 of u); c = sums * invc (fp32 -> bf16)
        for (int k0 = 0; k0 < MSGD; k0 += 32) {
            const float* sp = sums + (m0 + lr) * MSGD + k0 + lq * 8;
            float4 s0 = *reinterpret_cast<const float4*>(sp);
            float4 s1 = *reinterpret_cast<const float4*>(sp + 4);
            union { unsigned short u[8]; bf16x8 v; } ua;
            ua.u[0] = f2bf(s0.x * invc); ua.u[1] = f2bf(s0.y * invc);
            ua.u[2] = f2bf(s0.z * invc); ua.u[3] = f2bf(s0.w * invc);
            ua.u[4] = f2bf(s1.x * invc); ua.u[5] = f2bf(s1.y * invc);
            ua.u[6] = f2bf(s1.z * invc); ua.u[7] = f2bf(s1.w * invc);
            bf16x8 a = ua.v;
            bf16x8 br = ld8(wiht + (0 * 256 + t * 16 + lr) * 384 + 256 + k0 + lq * 8);
            bf16x8 bz = ld8(wiht + (1 * 256 + t * 16 + lr) * 384 + 256 + k0 + lq * 8);
            bf16x8 bn = ld8(wiht + (2 * 256 + t * 16 + lr) * 384 + 256 + k0 + lq * 8);
            air = mfma16(a, br, air); aiz = mfma16(a, bz, aiz); ain = mfma16(a, bn, ain);
        }
        // h @ Whh, fp32 h -> bf16 inline
        for (int k0 = 0; k0 < HDIM; k0 += 32) {
            bf16x8 a = ldf8(h + (m0 + lr) * HDIM + k0 + lq * 8);
            bf16x8 br = ld8(whht + (0 * 256 + t * 16 + lr) * HDIM + k0 + lq * 8);
            bf16x8 bz = ld8(whht + (1 * 256 + t * 16 + lr) * HDIM + k0 + lq * 8);
            bf16x8 bn = ld8(whht + (2 * 256 + t * 16 + lr) * HDIM + k0 + lq * 8);
            ahr = mfma16(a, br, ahr); ahz = mfma16(a, bz, ahz); ahn = mfma16(a, bn, ahn);
        }
        // gates (C layout: row = lq*4+r, col = t*16+lr)
        const int col = t * 16 + lr;
        float bir = bih[col],       bhr = bhh[col];
        float biz = bih[256 + col], bhz = bhh[256 + col];
        float bin = bih[512 + col], bhn = bhh[512 + col];
        for (int r = 0; r < 4; ++r) {
            int row = m0 + lq * 4 + r;
            float rg = sigmoidf_(air[r] + bir + ahr[r] + bhr);
            float zg = sigmoidf_(aiz[r] + biz + ahz[r] + bhz);
            float ng = tanhf_(ain[r] + bin + rg * (ahn[r] + bhn));
            float ho = h[row * HDIM + col];
            float hn = (1.0f - zg) * ng + zg * ho;
            out[HN_OFF + row * HDIM + col] = hn;
            hbuf[(lq * 4 + r) * 264 + col] = f2bf(hn);
        }
    }
    __syncthreads();
    // q = h_new @ out_W + out_b  (single 16-col tile)
    f32x4 acc = {0.f, 0.f, 0.f, 0.f};
    for (int k0 = 0; k0 < HDIM; k0 += 32) {
        bf16x8 a = ld8(hbuf + lr * 264 + k0 + lq * 8);
        bf16x8 b = ld8(wot + lr * HDIM + k0 + lq * 8);
        acc = mfma16(a, b, acc);
    }
    float bias = ob[lr];
    for (int r = 0; r < 4; ++r)
        out[Q_OFF + (m0 + lq * 4 + r) * ADIM + lr] = acc[r] + bias;
}

extern "C" void kernel_launch(void* const* d_in, const int* in_sizes, int n_in,
                              void* d_out, int out_size, void* d_ws, size_t ws_size,
                              hipStream_t stream) {
    const float* feat = (const float*)d_in[0];
    const float* h    = (const float*)d_in[1];
    const int* src    = (const int*)d_in[2];
    const int* dst    = (const int*)d_in[3];
    const float* w0   = (const float*)d_in[4];
    const float* b0   = (const float*)d_in[5];
    const float* w1   = (const float*)d_in[6];
    const float* b1   = (const float*)d_in[7];
    const float* wm   = (const float*)d_in[8];
    const float* mb   = (const float*)d_in[9];
    const float* wih  = (const float*)d_in[10];
    const float* whh  = (const float*)d_in[11];
    const float* bih  = (const float*)d_in[12];
    const float* bhh  = (const float*)d_in[13];
    const float* wo   = (const float*)d_in[14];
    const float* ob   = (const float*)d_in[15];

    char* ws = (char*)d_ws;
    unsigned short* w0t  = (unsigned short*)(ws + WS_W0T);
    unsigned short* w1t  = (unsigned short*)(ws + WS_W1T);
    unsigned short* wmt  = (unsigned short*)(ws + WS_WMT);
    unsigned short* wiht = (unsigned short*)(ws + WS_WIHT);
    unsigned short* whht = (unsigned short*)(ws + WS_WHHT);
    unsigned short* wot  = (unsigned short*)(ws + WS_WOT);
    unsigned short* X    = (unsigned short*)(ws + WS_X);
    unsigned short* Mn   = (unsigned short*)(ws + WS_MNODE);
    float* sums          = (float*)(ws + WS_SUMS);
    float* cnt           = (float*)(ws + WS_CNT);
    float* out           = (float*)d_out;

    hipLaunchKernelGGL(zero_kernel, dim3(2520), dim3(256), 0, stream, (float4*)(ws + WS_SUMS));
    hipLaunchKernelGGL(transpose_weights, dim3(512), dim3(256), 0, stream,
                       w0, w1, wm, wih, whh, wo, w0t, w1t, wmt, wiht, whht, wot);
    hipLaunchKernelGGL(enc_msg_kernel, dim3((NTILES + 3) / 4), dim3(256), 0, stream,
                       feat, h, w0t, b0, w1t, b1, wmt, mb, X, Mn);
    hipLaunchKernelGGL(edge_scatter, dim3((N_EDGES * 32) / 256), dim3(256), 0, stream,
                       src, dst, Mn, sums, cnt);
    hipLaunchKernelGGL(gru_out_kernel, dim3((NTILES + 3) / 4), dim3(256), 0, stream,
                       h, X, sums, cnt, wiht, whht, bih, bhh, wot, ob, out);
}

// Round 4
// 635.506 us; speedup vs baseline: 2.4879x; 2.4879x over previous
//
#include <hip/hip_runtime.h>

#define N_NODES 20000
#define N_EDGES 640000
#define OBS 64
#define HDIM 256
#define MSGD 128
#define ADIM 16
#define NTILES 1250            // N_NODES / 16
#define Q_OFF 0
#define HN_OFF (N_NODES * ADIM)   // 320000

typedef __bf16 bf16x8 __attribute__((ext_vector_type(8)));
typedef float  f32x4  __attribute__((ext_vector_type(4)));

__device__ __forceinline__ unsigned short f2bf(float f) {
    union { float f; unsigned int i; } v; v.f = f;
    unsigned int i = v.i;
    return (unsigned short)((i + 0x7fffu + ((i >> 16) & 1u)) >> 16);
}
__device__ __forceinline__ float bf2f(unsigned short u) {
    union { unsigned int i; float f; } v; v.i = ((unsigned int)u) << 16; return v.f;
}
__device__ __forceinline__ bf16x8 ld8(const unsigned short* p) {
    bf16x8 r;
    __builtin_memcpy(&r, __builtin_assume_aligned(p, 16), 16);
    return r;
}
// load 8 consecutive fp32, round to bf16 fragment in registers
__device__ __forceinline__ bf16x8 ldf8(const float* p) {
    const float4* q = (const float4*)__builtin_assume_aligned(p, 16);
    float4 a = q[0], b = q[1];
    union { unsigned short u[8]; bf16x8 v; } r;
    r.u[0] = f2bf(a.x); r.u[1] = f2bf(a.y); r.u[2] = f2bf(a.z); r.u[3] = f2bf(a.w);
    r.u[4] = f2bf(b.x); r.u[5] = f2bf(b.y); r.u[6] = f2bf(b.z); r.u[7] = f2bf(b.w);
    return r.v;
}
__device__ __forceinline__ f32x4 mfma16(bf16x8 a, bf16x8 b, f32x4 c) {
    return __builtin_amdgcn_mfma_f32_16x16x32_bf16(a, b, c, 0, 0, 0);
}
__device__ __forceinline__ float sigmoidf_(float x) { return 1.0f / (1.0f + __expf(-x)); }
__device__ __forceinline__ float tanhf_(float x) { return 2.0f / (1.0f + __expf(-2.0f * x)) - 1.0f; }

// ---------------- ws layout (bytes) ----------------
#define WS_W0T    0u          // 256x64  bf16 : 32768
#define WS_W1T    32768u      // 256x256 bf16 : 131072
#define WS_WMT    163840u     // 128x512 bf16 : 131072
#define WS_WIHT   294912u     // 768x384 bf16 : 589824
#define WS_WHHT   884736u     // 768x256 bf16 : 393216
#define WS_WOT    1277952u    // 16x256  bf16 : 8192
#define WS_X      1286144u    // 20000x256 bf16 : 10240000
#define WS_MNODE  11526144u   // 20000x128 bf16 : 5120000
#define WS_C      16646144u   // 20000x128 bf16 : 5120000
#define WS_DEG    21766144u   // 20000 int : 80000
#define WS_OFF    21846144u   // 20000 int : 80000
#define WS_CUR    21926144u   // 20000 int : 80000
#define WS_BUCKET 22006144u   // 640000 int : 2560000  (end 24566144)

// transpose fp32 weights into bf16 N-major (K contiguous) layouts; also zero deg
__global__ __launch_bounds__(256) void transpose_weights(
    const float* w0, const float* w1, const float* wm,
    const float* wih, const float* whh, const float* wo,
    unsigned short* w0t, unsigned short* w1t, unsigned short* wmt,
    unsigned short* wiht, unsigned short* whht, unsigned short* wot,
    int* deg)
{
    int tid = blockIdx.x * 256 + threadIdx.x;
    int np = gridDim.x * 256;
    for (int i = tid; i < N_NODES; i += np)   deg[i] = 0;
    for (int i = tid; i < 256 * 64; i += np)  { int n = i / 64,  k = i % 64;  w0t[i]  = f2bf(w0[k * 256 + n]); }
    for (int i = tid; i < 256 * 256; i += np) { int n = i / 256, k = i % 256; w1t[i]  = f2bf(w1[k * 256 + n]); }
    for (int i = tid; i < 128 * 512; i += np) { int n = i / 512, k = i % 512; wmt[i]  = f2bf(wm[k * 128 + n]); }
    for (int i = tid; i < 768 * 384; i += np) { int n = i / 384, k = i % 384; wiht[i] = f2bf(wih[k * 768 + n]); }
    for (int i = tid; i < 768 * 256; i += np) { int n = i / 256, k = i % 256; whht[i] = f2bf(whh[k * 768 + n]); }
    for (int i = tid; i < 16 * 256; i += np)  { int n = i / 256, k = i % 256; wot[i]  = f2bf(wo[k * 16 + n]); }
}

__global__ __launch_bounds__(256) void hist_kernel(const int* __restrict__ dst, int* __restrict__ deg) {
    int i = blockIdx.x * 256 + threadIdx.x;
    if (i < N_EDGES) atomicAdd(&deg[dst[i]], 1);
}

// single-block exclusive scan of deg -> off (and cursor copy). 1024 thr x 20 elems.
__global__ __launch_bounds__(1024) void scan_kernel(const int* __restrict__ deg,
                                                    int* __restrict__ off, int* __restrict__ cur) {
    __shared__ int part[1024];
    const int t = threadIdx.x;
    const int base = t * 20;
    int s = 0;
    #pragma unroll
    for (int i = 0; i < 20; ++i) { int idx = base + i; if (idx < N_NODES) s += deg[idx]; }
    part[t] = s;
    __syncthreads();
    int acc = s;
    for (int d = 1; d < 1024; d <<= 1) {
        int v = (t >= d) ? part[t - d] : 0;
        __syncthreads();
        acc += v; part[t] = acc;
        __syncthreads();
    }
    int run = acc - s;   // exclusive base of this chunk
    for (int i = 0; i < 20; ++i) {
        int idx = base + i;
        if (idx < N_NODES) { off[idx] = run; cur[idx] = run; run += deg[idx]; }
    }
}

__global__ __launch_bounds__(256) void scatter_idx(const int* __restrict__ src, const int* __restrict__ dst,
                                                   int* __restrict__ cur, int* __restrict__ bucket) {
    int i = blockIdx.x * 256 + threadIdx.x;
    if (i < N_EDGES) {
        int d = dst[i];
        int pos = atomicAdd(&cur[d], 1);
        bucket[pos] = src[i];
    }
}

// one wave per node: gather Mnode rows of incoming edges, mean, write bf16 C row.
// lane owns 2 packed bf16 columns (one uint); wave covers the full 256B row coalesced.
__global__ __launch_bounds__(256) void aggregate_kernel(
    const int* __restrict__ off, const int* __restrict__ deg,
    const int* __restrict__ bucket, const unsigned short* __restrict__ Mnode,
    unsigned short* __restrict__ C)
{
    const int wave = threadIdx.x >> 6;
    const int lane = threadIdx.x & 63;
    const int node = blockIdx.x * 4 + wave;
    if (node >= N_NODES) return;
    const int o = off[node], dg = deg[node];
    float s0 = 0.f, s1 = 0.f;
    const unsigned int* mn = (const unsigned int*)Mnode;
    for (int j = 0; j < dg; ++j) {
        int sidx = bucket[o + j];                 // wave-uniform scalar load
        unsigned int pk = mn[sidx * 64 + lane];   // coalesced 256B row read
        s0 += bf2f((unsigned short)(pk & 0xffffu));
        s1 += bf2f((unsigned short)(pk >> 16));
    }
    float invc = 1.0f / fmaxf((float)dg, 1.0f);
    unsigned int outpk = ((unsigned int)f2bf(s1 * invc) << 16) | (unsigned int)f2bf(s0 * invc);
    ((unsigned int*)C)[node * 64 + lane] = outpk;
}

// enc0 -> relu -> enc1 -> relu -> per-node message. One wave = 16 node rows.
__global__ __launch_bounds__(256) void enc_msg_kernel(
    const float* __restrict__ feat, const float* __restrict__ h,
    const unsigned short* __restrict__ w0t, const float* __restrict__ b0,
    const unsigned short* __restrict__ w1t, const float* __restrict__ b1,
    const unsigned short* __restrict__ wmt, const float* __restrict__ mb,
    unsigned short* __restrict__ X, unsigned short* __restrict__ Mnode)
{
    const int wave = threadIdx.x >> 6;
    const int lane = threadIdx.x & 63;
    int tile = blockIdx.x * 4 + wave;
    if (tile >= NTILES) tile = NTILES - 1;   // clamp: duplicate work, barrier-safe
    const int m0 = tile * 16;
    const int lr = lane & 15;        // A-row / B-col / C-col
    const int lq = lane >> 4;        // k-quad (A/B), row-quad (C)

    __shared__ __align__(16) unsigned short lds[4][2][16 * 264];  // per-wave x0/x1 (pad 264)
    unsigned short* x0buf = lds[wave][0];
    unsigned short* x1buf = lds[wave][1];

    // ---- Stage A: X0 = relu(feat @ W0 + b0) -> LDS ----
    for (int t = 0; t < 16; ++t) {
        f32x4 acc = {0.f, 0.f, 0.f, 0.f};
        for (int k0 = 0; k0 < OBS; k0 += 32) {
            bf16x8 a = ldf8(feat + (m0 + lr) * OBS + k0 + lq * 8);
            bf16x8 b = ld8(w0t + (t * 16 + lr) * OBS + k0 + lq * 8);
            acc = mfma16(a, b, acc);
        }
        float bias = b0[t * 16 + lr];
        for (int r = 0; r < 4; ++r) {
            float v = fmaxf(acc[r] + bias, 0.f);
            x0buf[(lq * 4 + r) * 264 + t * 16 + lr] = f2bf(v);
        }
    }
    __syncthreads();
    // ---- Stage B: X = relu(X0 @ W1 + b1) -> LDS + global ----
    for (int t = 0; t < 16; ++t) {
        f32x4 acc = {0.f, 0.f, 0.f, 0.f};
        for (int k0 = 0; k0 < HDIM; k0 += 32) {
            bf16x8 a = ld8(x0buf + lr * 264 + k0 + lq * 8);
            bf16x8 b = ld8(w1t + (t * 16 + lr) * HDIM + k0 + lq * 8);
            acc = mfma16(a, b, acc);
        }
        float bias = b1[t * 16 + lr];
        for (int r = 0; r < 4; ++r) {
            float v = fmaxf(acc[r] + bias, 0.f);
            unsigned short xb = f2bf(v);
            X[(m0 + lq * 4 + r) * HDIM + t * 16 + lr] = xb;
            x1buf[(lq * 4 + r) * 264 + t * 16 + lr] = xb;
        }
    }
    __syncthreads();
    // ---- Stage C: Mnode = X @ Wx + h @ Wh + mb -> global ----
    for (int t = 0; t < 8; ++t) {
        f32x4 acc = {0.f, 0.f, 0.f, 0.f};
        for (int k0 = 0; k0 < HDIM; k0 += 32) {   // X part, from LDS copy
            bf16x8 a = ld8(x1buf + lr * 264 + k0 + lq * 8);
            bf16x8 b = ld8(wmt + (t * 16 + lr) * 512 + k0 + lq * 8);
            acc = mfma16(a, b, acc);
        }
        for (int k0 = 0; k0 < HDIM; k0 += 32) {   // h part, fp32 -> bf16 inline
            bf16x8 a = ldf8(h + (m0 + lr) * HDIM + k0 + lq * 8);
            bf16x8 b = ld8(wmt + (t * 16 + lr) * 512 + 256 + k0 + lq * 8);
            acc = mfma16(a, b, acc);
        }
        float bias = mb[t * 16 + lr];
        for (int r = 0; r < 4; ++r)
            Mnode[(m0 + lq * 4 + r) * MSGD + t * 16 + lr] = f2bf(acc[r] + bias);
    }
}

// GRU cell + output head. One wave = 16 node rows.
__global__ __launch_bounds__(256) void gru_out_kernel(
    const float* __restrict__ h, const unsigned short* __restrict__ X,
    const unsigned short* __restrict__ C,
    const unsigned short* __restrict__ wiht, const unsigned short* __restrict__ whht,
    const float* __restrict__ bih, const float* __restrict__ bhh,
    const unsigned short* __restrict__ wot, const float* __restrict__ ob,
    float* __restrict__ out)
{
    const int wave = threadIdx.x >> 6;
    const int lane = threadIdx.x & 63;
    int tile = blockIdx.x * 4 + wave;
    if (tile >= NTILES) tile = NTILES - 1;   // clamp (barrier-safe)
    const int m0 = tile * 16;
    const int lr = lane & 15;
    const int lq = lane >> 4;

    __shared__ __align__(16) unsigned short lds[4][16 * 264];
    unsigned short* hbuf = lds[wave];

    for (int t = 0; t < 16; ++t) {
        f32x4 air = {0.f,0.f,0.f,0.f}, aiz = {0.f,0.f,0.f,0.f}, ain = {0.f,0.f,0.f,0.f};
        f32x4 ahr = {0.f,0.f,0.f,0.f}, ahz = {0.f,0.f,0.f,0.f}, ahn = {0.f,0.f,0.f,0.f};
        // u @ Wih, X part (k = 0..255 of u), X already bf16
        for (int k0 = 0; k0 < HDIM; k0 += 32) {
            bf16x8 a = ld8(X + (m0 + lr) * HDIM + k0 + lq * 8);
            bf16x8 br = ld8(wiht + (0 * 256 + t * 16 + lr) * 384 + k0 + lq * 8);
            bf16x8 bz = ld8(wiht + (1 * 256 + t * 16 + lr) * 384 + k0 + lq * 8);
            bf16x8 bn = ld8(wiht + (2 * 256 + t * 16 + lr) * 384 + k0 + lq * 8);
            air = mfma16(a, br, air); aiz = mfma16(a, bz, aiz); ain = mfma16(a, bn, ain);
        }
        // u @ Wih, c part (k = 256..383 of u); C already bf16
        for (int k0 = 0; k0 < MSGD; k0 += 32) {
            bf16x8 a = ld8(C + (m0 + lr) * MSGD + k0 + lq * 8);
            bf16x8 br = ld8(wiht + (0 * 256 + t * 16 + lr) * 384 + 256 + k0 + lq * 8);
            bf16x8 bz = ld8(wiht + (1 * 256 + t * 16 + lr) * 384 + 256 + k0 + lq * 8);
            bf16x8 bn = ld8(wiht + (2 * 256 + t * 16 + lr) * 384 + 256 + k0 + lq * 8);
            air = mfma16(a, br, air); aiz = mfma16(a, bz, aiz); ain = mfma16(a, bn, ain);
        }
        // h @ Whh, fp32 h -> bf16 inline
        for (int k0 = 0; k0 < HDIM; k0 += 32) {
            bf16x8 a = ldf8(h + (m0 + lr) * HDIM + k0 + lq * 8);
            bf16x8 br = ld8(whht + (0 * 256 + t * 16 + lr) * HDIM + k0 + lq * 8);
            bf16x8 bz = ld8(whht + (1 * 256 + t * 16 + lr) * HDIM + k0 + lq * 8);
            bf16x8 bn = ld8(whht + (2 * 256 + t * 16 + lr) * HDIM + k0 + lq * 8);
            ahr = mfma16(a, br, ahr); ahz = mfma16(a, bz, ahz); ahn = mfma16(a, bn, ahn);
        }
        // gates (C layout: row = lq*4+r, col = t*16+lr)
        const int col = t * 16 + lr;
        float bir = bih[col],       bhr = bhh[col];
        float biz = bih[256 + col], bhz = bhh[256 + col];
        float bin = bih[512 + col], bhn = bhh[512 + col];
        for (int r = 0; r < 4; ++r) {
            int row = m0 + lq * 4 + r;
            float rg = sigmoidf_(air[r] + bir + ahr[r] + bhr);
            float zg = sigmoidf_(aiz[r] + biz + ahz[r] + bhz);
            float ng = tanhf_(ain[r] + bin + rg * (ahn[r] + bhn));
            float ho = h[row * HDIM + col];
            float hn = (1.0f - zg) * ng + zg * ho;
            out[HN_OFF + row * HDIM + col] = hn;
            hbuf[(lq * 4 + r) * 264 + col] = f2bf(hn);
        }
    }
    __syncthreads();
    // q = h_new @ out_W + out_b  (single 16-col tile)
    f32x4 acc = {0.f, 0.f, 0.f, 0.f};
    for (int k0 = 0; k0 < HDIM; k0 += 32) {
        bf16x8 a = ld8(hbuf + lr * 264 + k0 + lq * 8);
        bf16x8 b = ld8(wot + lr * HDIM + k0 + lq * 8);
        acc = mfma16(a, b, acc);
    }
    float bias = ob[lr];
    for (int r = 0; r < 4; ++r)
        out[Q_OFF + (m0 + lq * 4 + r) * ADIM + lr] = acc[r] + bias;
}

extern "C" void kernel_launch(void* const* d_in, const int* in_sizes, int n_in,
                              void* d_out, int out_size, void* d_ws, size_t ws_size,
                              hipStream_t stream) {
    const float* feat = (const float*)d_in[0];
    const float* h    = (const float*)d_in[1];
    const int* src    = (const int*)d_in[2];
    const int* dst    = (const int*)d_in[3];
    const float* w0   = (const float*)d_in[4];
    const float* b0   = (const float*)d_in[5];
    const float* w1   = (const float*)d_in[6];
    const float* b1   = (const float*)d_in[7];
    const float* wm   = (const float*)d_in[8];
    const float* mb   = (const float*)d_in[9];
    const float* wih  = (const float*)d_in[10];
    const float* whh  = (const float*)d_in[11];
    const float* bih  = (const float*)d_in[12];
    const float* bhh  = (const float*)d_in[13];
    const float* wo   = (const float*)d_in[14];
    const float* ob   = (const float*)d_in[15];

    char* ws = (char*)d_ws;
    unsigned short* w0t  = (unsigned short*)(ws + WS_W0T);
    unsigned short* w1t  = (unsigned short*)(ws + WS_W1T);
    unsigned short* wmt  = (unsigned short*)(ws + WS_WMT);
    unsigned short* wiht = (unsigned short*)(ws + WS_WIHT);
    unsigned short* whht = (unsigned short*)(ws + WS_WHHT);
    unsigned short* wot  = (unsigned short*)(ws + WS_WOT);
    unsigned short* X    = (unsigned short*)(ws + WS_X);
    unsigned short* Mn   = (unsigned short*)(ws + WS_MNODE);
    unsigned short* C    = (unsigned short*)(ws + WS_C);
    int* deg             = (int*)(ws + WS_DEG);
    int* off             = (int*)(ws + WS_OFF);
    int* cur             = (int*)(ws + WS_CUR);
    int* bucket          = (int*)(ws + WS_BUCKET);
    float* out           = (float*)d_out;

    hipLaunchKernelGGL(transpose_weights, dim3(512), dim3(256), 0, stream,
                       w0, w1, wm, wih, whh, wo, w0t, w1t, wmt, wiht, whht, wot, deg);
    hipLaunchKernelGGL(hist_kernel, dim3((N_EDGES + 255) / 256), dim3(256), 0, stream, dst, deg);
    hipLaunchKernelGGL(scan_kernel, dim3(1), dim3(1024), 0, stream, deg, off, cur);
    hipLaunchKernelGGL(scatter_idx, dim3((N_EDGES + 255) / 256), dim3(256), 0, stream, src, dst, cur, bucket);
    hipLaunchKernelGGL(enc_msg_kernel, dim3((NTILES + 3) / 4), dim3(256), 0, stream,
                       feat, h, w0t, b0, w1t, b1, wmt, mb, X, Mn);
    hipLaunchKernelGGL(aggregate_kernel, dim3((N_NODES + 3) / 4), dim3(256), 0, stream,
                       off, deg, bucket, Mn, C);
    hipLaunchKernelGGL(gru_out_kernel, dim3((NTILES + 3) / 4), dim3(256), 0, stream,
                       h, X, C, wiht, whht, bih, bhh, wot, ob, out);
}

// Round 5
// 404.320 us; speedup vs baseline: 3.9104x; 1.5718x over previous
//
#include <hip/hip_runtime.h>

#define N_NODES 20000
#define N_EDGES 640000
#define OBS 64
#define HDIM 256
#define MSGD 128
#define ADIM 16
#define Q_OFF 0
#define HN_OFF (N_NODES * ADIM)   // 320000

typedef __bf16 bf16x8 __attribute__((ext_vector_type(8)));
typedef float  f32x4  __attribute__((ext_vector_type(4)));

__device__ __forceinline__ unsigned short f2bf(float f) {
    union { float f; unsigned int i; } v; v.f = f;
    unsigned int i = v.i;
    return (unsigned short)((i + 0x7fffu + ((i >> 16) & 1u)) >> 16);
}
__device__ __forceinline__ float bf2f(unsigned short u) {
    union { unsigned int i; float f; } v; v.i = ((unsigned int)u) << 16; return v.f;
}
__device__ __forceinline__ bf16x8 ld8(const unsigned short* p) {
    bf16x8 r;
    __builtin_memcpy(&r, __builtin_assume_aligned(p, 16), 16);
    return r;
}
__device__ __forceinline__ f32x4 mfma16(bf16x8 a, bf16x8 b, f32x4 c) {
    return __builtin_amdgcn_mfma_f32_16x16x32_bf16(a, b, c, 0, 0, 0);
}
__device__ __forceinline__ float sigmoidf_(float x) { return 1.0f / (1.0f + __expf(-x)); }
__device__ __forceinline__ float tanhf_(float x) { return 2.0f / (1.0f + __expf(-2.0f * x)) - 1.0f; }

// ---------------- ws layout (bytes) ----------------
#define WS_W0T    0u          // 256x64  bf16
#define WS_W1T    32768u      // 256x256 bf16
#define WS_WMT    163840u     // 128x512 bf16
#define WS_WGT    294912u     // 768x640 bf16 (combined [Wih;Whh] gate-major, K=640)
#define WS_WOT    1277952u    // 16x256  bf16
#define WS_FEATB  1286144u    // 20000x64 bf16
#define WS_HB     3846144u    // 20000x256 bf16
#define WS_X0     14086144u   // 20000x256 bf16
#define WS_X      24326144u   // 20000x256 bf16
#define WS_MN     34566144u   // 20000x128 bf16
#define WS_C      39686144u   // 20000x128 bf16
#define WS_HNEWB  44806144u   // 20000x256 bf16
#define WS_DEG    55046144u   // 20000 int
#define WS_OFF    55126144u   // 20000 int
#define WS_CUR    55206144u   // 20000 int
#define WS_BUCKET 55286144u   // 640000 int (end 57846144)

// convert fp32 feat/h to bf16 (16B packed stores), zero deg
__global__ __launch_bounds__(256) void prep_kernel(
    const float* __restrict__ feat, const float* __restrict__ h,
    unsigned short* __restrict__ featb, unsigned short* __restrict__ hb,
    int* __restrict__ deg)
{
    int tid = blockIdx.x * 256 + threadIdx.x;
    int np = gridDim.x * 256;
    for (int i = tid; i < N_NODES; i += np) deg[i] = 0;
    for (int i = tid; i < N_NODES * OBS / 8; i += np) {
        const float4* p = (const float4*)(feat + i * 8);
        float4 a = p[0], b = p[1];
        union { unsigned short u[8]; uint4 v; } r;
        r.u[0]=f2bf(a.x); r.u[1]=f2bf(a.y); r.u[2]=f2bf(a.z); r.u[3]=f2bf(a.w);
        r.u[4]=f2bf(b.x); r.u[5]=f2bf(b.y); r.u[6]=f2bf(b.z); r.u[7]=f2bf(b.w);
        ((uint4*)(featb + i * 8))[0] = r.v;
    }
    for (int i = tid; i < N_NODES * HDIM / 8; i += np) {
        const float4* p = (const float4*)(h + i * 8);
        float4 a = p[0], b = p[1];
        union { unsigned short u[8]; uint4 v; } r;
        r.u[0]=f2bf(a.x); r.u[1]=f2bf(a.y); r.u[2]=f2bf(a.z); r.u[3]=f2bf(a.w);
        r.u[4]=f2bf(b.x); r.u[5]=f2bf(b.y); r.u[6]=f2bf(b.z); r.u[7]=f2bf(b.w);
        ((uint4*)(hb + i * 8))[0] = r.v;
    }
}

// transpose fp32 weights into bf16 N-major (K contiguous) layouts
__global__ __launch_bounds__(256) void transpose_weights(
    const float* w0, const float* w1, const float* wm,
    const float* wih, const float* whh, const float* wo,
    unsigned short* w0t, unsigned short* w1t, unsigned short* wmt,
    unsigned short* wgt, unsigned short* wot)
{
    int tid = blockIdx.x * 256 + threadIdx.x;
    int np = gridDim.x * 256;
    for (int i = tid; i < 256 * 64; i += np)  { int n = i / 64,  k = i % 64;  w0t[i] = f2bf(w0[k * 256 + n]); }
    for (int i = tid; i < 256 * 256; i += np) { int n = i / 256, k = i % 256; w1t[i] = f2bf(w1[k * 256 + n]); }
    for (int i = tid; i < 128 * 512; i += np) { int n = i / 512, k = i % 512; wmt[i] = f2bf(wm[k * 128 + n]); }
    for (int i = tid; i < 768 * 640; i += np) {
        int n = i / 640, k = i % 640;
        float v = (k < 384) ? wih[k * 768 + n] : whh[(k - 384) * 768 + n];
        wgt[i] = f2bf(v);
    }
    for (int i = tid; i < 16 * 256; i += np)  { int n = i / 256, k = i % 256; wot[i] = f2bf(wo[k * 16 + n]); }
}

__global__ __launch_bounds__(256) void hist_kernel(const int* __restrict__ dst, int* __restrict__ deg) {
    int i = blockIdx.x * 256 + threadIdx.x;
    if (i < N_EDGES) atomicAdd(&deg[dst[i]], 1);
}

// single-block exclusive scan of deg -> off (and cursor copy). 1024 thr x 20 elems.
__global__ __launch_bounds__(1024) void scan_kernel(const int* __restrict__ deg,
                                                    int* __restrict__ off, int* __restrict__ cur) {
    __shared__ int part[1024];
    const int t = threadIdx.x;
    const int base = t * 20;
    int s = 0;
    #pragma unroll
    for (int i = 0; i < 20; ++i) { int idx = base + i; if (idx < N_NODES) s += deg[idx]; }
    part[t] = s;
    __syncthreads();
    int acc = s;
    for (int d = 1; d < 1024; d <<= 1) {
        int v = (t >= d) ? part[t - d] : 0;
        __syncthreads();
        acc += v; part[t] = acc;
        __syncthreads();
    }
    int run = acc - s;
    for (int i = 0; i < 20; ++i) {
        int idx = base + i;
        if (idx < N_NODES) { off[idx] = run; cur[idx] = run; run += deg[idx]; }
    }
}

__global__ __launch_bounds__(256) void scatter_idx(const int* __restrict__ src, const int* __restrict__ dst,
                                                   int* __restrict__ cur, int* __restrict__ bucket) {
    int i = blockIdx.x * 256 + threadIdx.x;
    if (i < N_EDGES) {
        int d = dst[i];
        int pos = atomicAdd(&cur[d], 1);
        bucket[pos] = src[i];
    }
}

// ---- GEMM wave helpers: wave = (m64 rowblock of 64, 16-col tile), M=64 via 4 A-frags ----

// enc0: X0 = relu(featb @ W0T + b0). waves = 313*16
__global__ __launch_bounds__(256) void enc0_kernel(
    const unsigned short* __restrict__ featb, const unsigned short* __restrict__ w0t,
    const float* __restrict__ b0, unsigned short* __restrict__ X0)
{
    const int w = blockIdx.x * 4 + (threadIdx.x >> 6);
    const int lane = threadIdx.x & 63, lr = lane & 15, lq = lane >> 4;
    const int m64 = w >> 4, t = w & 15;
    const int col = t * 16 + lr;
    int rowA[4];
    #pragma unroll
    for (int mf = 0; mf < 4; ++mf) { int r = m64 * 64 + mf * 16 + lr; rowA[mf] = r < N_NODES ? r : N_NODES - 1; }
    f32x4 acc[4] = {{0,0,0,0},{0,0,0,0},{0,0,0,0},{0,0,0,0}};
    for (int k0 = 0; k0 < OBS; k0 += 32) {
        bf16x8 b = ld8(w0t + col * OBS + k0 + lq * 8);
        #pragma unroll
        for (int mf = 0; mf < 4; ++mf) {
            bf16x8 a = ld8(featb + rowA[mf] * OBS + k0 + lq * 8);
            acc[mf] = mfma16(a, b, acc[mf]);
        }
    }
    float bias = b0[col];
    #pragma unroll
    for (int mf = 0; mf < 4; ++mf)
        #pragma unroll
        for (int r = 0; r < 4; ++r) {
            int row = m64 * 64 + mf * 16 + lq * 4 + r;
            if (row < N_NODES) X0[row * HDIM + col] = f2bf(fmaxf(acc[mf][r] + bias, 0.f));
        }
}

// enc1: X = relu(X0 @ W1T + b1). waves = 313*16
__global__ __launch_bounds__(256) void enc1_kernel(
    const unsigned short* __restrict__ X0, const unsigned short* __restrict__ w1t,
    const float* __restrict__ b1, unsigned short* __restrict__ X)
{
    const int w = blockIdx.x * 4 + (threadIdx.x >> 6);
    const int lane = threadIdx.x & 63, lr = lane & 15, lq = lane >> 4;
    const int m64 = w >> 4, t = w & 15;
    const int col = t * 16 + lr;
    int rowA[4];
    #pragma unroll
    for (int mf = 0; mf < 4; ++mf) { int r = m64 * 64 + mf * 16 + lr; rowA[mf] = r < N_NODES ? r : N_NODES - 1; }
    f32x4 acc[4] = {{0,0,0,0},{0,0,0,0},{0,0,0,0},{0,0,0,0}};
    for (int k0 = 0; k0 < HDIM; k0 += 32) {
        bf16x8 b = ld8(w1t + col * HDIM + k0 + lq * 8);
        #pragma unroll
        for (int mf = 0; mf < 4; ++mf) {
            bf16x8 a = ld8(X0 + rowA[mf] * HDIM + k0 + lq * 8);
            acc[mf] = mfma16(a, b, acc[mf]);
        }
    }
    float bias = b1[col];
    #pragma unroll
    for (int mf = 0; mf < 4; ++mf)
        #pragma unroll
        for (int r = 0; r < 4; ++r) {
            int row = m64 * 64 + mf * 16 + lq * 4 + r;
            if (row < N_NODES) X[row * HDIM + col] = f2bf(fmaxf(acc[mf][r] + bias, 0.f));
        }
}

// msg: Mnode = X @ Wx + hb @ Wh + mb. waves = 313*8 (N=128)
__global__ __launch_bounds__(256) void msg_kernel(
    const unsigned short* __restrict__ X, const unsigned short* __restrict__ hb,
    const unsigned short* __restrict__ wmt, const float* __restrict__ mb,
    unsigned short* __restrict__ Mnode)
{
    const int w = blockIdx.x * 4 + (threadIdx.x >> 6);
    const int lane = threadIdx.x & 63, lr = lane & 15, lq = lane >> 4;
    const int m64 = w >> 3, t = w & 7;
    const int col = t * 16 + lr;
    int rowA[4];
    #pragma unroll
    for (int mf = 0; mf < 4; ++mf) { int r = m64 * 64 + mf * 16 + lr; rowA[mf] = r < N_NODES ? r : N_NODES - 1; }
    f32x4 acc[4] = {{0,0,0,0},{0,0,0,0},{0,0,0,0},{0,0,0,0}};
    for (int k0 = 0; k0 < HDIM; k0 += 32) {          // X part (k 0..255)
        bf16x8 b = ld8(wmt + col * 512 + k0 + lq * 8);
        #pragma unroll
        for (int mf = 0; mf < 4; ++mf) {
            bf16x8 a = ld8(X + rowA[mf] * HDIM + k0 + lq * 8);
            acc[mf] = mfma16(a, b, acc[mf]);
        }
    }
    for (int k0 = 0; k0 < HDIM; k0 += 32) {          // h part (k 256..511)
        bf16x8 b = ld8(wmt + col * 512 + 256 + k0 + lq * 8);
        #pragma unroll
        for (int mf = 0; mf < 4; ++mf) {
            bf16x8 a = ld8(hb + rowA[mf] * HDIM + k0 + lq * 8);
            acc[mf] = mfma16(a, b, acc[mf]);
        }
    }
    float bias = mb[col];
    #pragma unroll
    for (int mf = 0; mf < 4; ++mf)
        #pragma unroll
        for (int r = 0; r < 4; ++r) {
            int row = m64 * 64 + mf * 16 + lq * 4 + r;
            if (row < N_NODES) Mnode[row * MSGD + col] = f2bf(acc[mf][r] + bias);
        }
}

// one wave per node: gather Mnode rows of incoming edges, mean, write bf16 C row.
__global__ __launch_bounds__(256) void aggregate_kernel(
    const int* __restrict__ off, const int* __restrict__ deg,
    const int* __restrict__ bucket, const unsigned short* __restrict__ Mnode,
    unsigned short* __restrict__ C)
{
    const int wave = threadIdx.x >> 6;
    const int lane = threadIdx.x & 63;
    const int node = blockIdx.x * 4 + wave;
    if (node >= N_NODES) return;
    const int o = off[node], dg = deg[node];
    float s0 = 0.f, s1 = 0.f;
    const unsigned int* mn = (const unsigned int*)Mnode;
    int j = 0;
    for (; j + 4 <= dg; j += 4) {
        int i0 = bucket[o + j], i1 = bucket[o + j + 1], i2 = bucket[o + j + 2], i3 = bucket[o + j + 3];
        unsigned int p0 = mn[i0 * 64 + lane], p1 = mn[i1 * 64 + lane];
        unsigned int p2 = mn[i2 * 64 + lane], p3 = mn[i3 * 64 + lane];
        s0 += bf2f((unsigned short)(p0 & 0xffffu)) + bf2f((unsigned short)(p1 & 0xffffu))
            + bf2f((unsigned short)(p2 & 0xffffu)) + bf2f((unsigned short)(p3 & 0xffffu));
        s1 += bf2f((unsigned short)(p0 >> 16)) + bf2f((unsigned short)(p1 >> 16))
            + bf2f((unsigned short)(p2 >> 16)) + bf2f((unsigned short)(p3 >> 16));
    }
    for (; j < dg; ++j) {
        int sidx = bucket[o + j];
        unsigned int pk = mn[sidx * 64 + lane];
        s0 += bf2f((unsigned short)(pk & 0xffffu));
        s1 += bf2f((unsigned short)(pk >> 16));
    }
    float invc = 1.0f / fmaxf((float)dg, 1.0f);
    unsigned int outpk = ((unsigned int)f2bf(s1 * invc) << 16) | (unsigned int)f2bf(s0 * invc);
    ((unsigned int*)C)[node * 64 + lane] = outpk;
}

// GRU gates + h_new. wave = (m64, t). K=640 combined [X(256)|C(128)|h(256)].
// wgt row n = gate*256 + col, gates: 0=r 1=z 2=n. waves = 313*16
__global__ __launch_bounds__(256) void gru_kernel(
    const unsigned short* __restrict__ X, const unsigned short* __restrict__ Cb,
    const unsigned short* __restrict__ hb, const float* __restrict__ h,
    const unsigned short* __restrict__ wgt,
    const float* __restrict__ bih, const float* __restrict__ bhh,
    unsigned short* __restrict__ Hb, float* __restrict__ out)
{
    const int w = blockIdx.x * 4 + (threadIdx.x >> 6);
    const int lane = threadIdx.x & 63, lr = lane & 15, lq = lane >> 4;
    const int m64 = w >> 4, t = w & 15;
    const int col = t * 16 + lr;
    int rowA[4];
    #pragma unroll
    for (int mf = 0; mf < 4; ++mf) { int r = m64 * 64 + mf * 16 + lr; rowA[mf] = r < N_NODES ? r : N_NODES - 1; }

    f32x4 ar[4]  = {{0,0,0,0},{0,0,0,0},{0,0,0,0},{0,0,0,0}};   // r gate (i+h merged)
    f32x4 az[4]  = {{0,0,0,0},{0,0,0,0},{0,0,0,0},{0,0,0,0}};   // z gate (i+h merged)
    f32x4 ani[4] = {{0,0,0,0},{0,0,0,0},{0,0,0,0},{0,0,0,0}};   // n gate, input part
    f32x4 anh[4] = {{0,0,0,0},{0,0,0,0},{0,0,0,0},{0,0,0,0}};   // n gate, hidden part

    const unsigned short* wr = wgt + (0 * 256 + col) * 640;
    const unsigned short* wz = wgt + (1 * 256 + col) * 640;
    const unsigned short* wn = wgt + (2 * 256 + col) * 640;

    // X part: k 0..255
    for (int k0 = 0; k0 < 256; k0 += 32) {
        bf16x8 br = ld8(wr + k0 + lq * 8);
        bf16x8 bz = ld8(wz + k0 + lq * 8);
        bf16x8 bn = ld8(wn + k0 + lq * 8);
        #pragma unroll
        for (int mf = 0; mf < 4; ++mf) {
            bf16x8 a = ld8(X + rowA[mf] * HDIM + k0 + lq * 8);
            ar[mf] = mfma16(a, br, ar[mf]);
            az[mf] = mfma16(a, bz, az[mf]);
            ani[mf] = mfma16(a, bn, ani[mf]);
        }
    }
    // C part: k 256..383
    for (int k0 = 0; k0 < 128; k0 += 32) {
        bf16x8 br = ld8(wr + 256 + k0 + lq * 8);
        bf16x8 bz = ld8(wz + 256 + k0 + lq * 8);
        bf16x8 bn = ld8(wn + 256 + k0 + lq * 8);
        #pragma unroll
        for (int mf = 0; mf < 4; ++mf) {
            bf16x8 a = ld8(Cb + rowA[mf] * MSGD + k0 + lq * 8);
            ar[mf] = mfma16(a, br, ar[mf]);
            az[mf] = mfma16(a, bz, az[mf]);
            ani[mf] = mfma16(a, bn, ani[mf]);
        }
    }
    // h part: k 384..639 (n-gate goes to separate accumulator)
    for (int k0 = 0; k0 < 256; k0 += 32) {
        bf16x8 br = ld8(wr + 384 + k0 + lq * 8);
        bf16x8 bz = ld8(wz + 384 + k0 + lq * 8);
        bf16x8 bn = ld8(wn + 384 + k0 + lq * 8);
        #pragma unroll
        for (int mf = 0; mf < 4; ++mf) {
            bf16x8 a = ld8(hb + rowA[mf] * HDIM + k0 + lq * 8);
            ar[mf] = mfma16(a, br, ar[mf]);
            az[mf] = mfma16(a, bz, az[mf]);
            anh[mf] = mfma16(a, bn, anh[mf]);
        }
    }

    const float bir = bih[col] + bhh[col];          // r: biases merge
    const float biz = bih[256 + col] + bhh[256 + col];
    const float bin = bih[512 + col];
    const float bhn = bhh[512 + col];
    #pragma unroll
    for (int mf = 0; mf < 4; ++mf)
        #pragma unroll
        for (int r = 0; r < 4; ++r) {
            int row = m64 * 64 + mf * 16 + lq * 4 + r;
            if (row < N_NODES) {
                float rg = sigmoidf_(ar[mf][r] + bir);
                float zg = sigmoidf_(az[mf][r] + biz);
                float ng = tanhf_(ani[mf][r] + bin + rg * (anh[mf][r] + bhn));
                float ho = h[row * HDIM + col];
                float hn = (1.0f - zg) * ng + zg * ho;
                out[HN_OFF + row * HDIM + col] = hn;
                Hb[row * HDIM + col] = f2bf(hn);
            }
        }
}

// q = h_new @ out_W + out_b. one wave per 16-row tile.
__global__ __launch_bounds__(256) void q_kernel(
    const unsigned short* __restrict__ Hb, const unsigned short* __restrict__ wot,
    const float* __restrict__ ob, float* __restrict__ out)
{
    int w = blockIdx.x * 4 + (threadIdx.x >> 6);
    if (w >= N_NODES / 16) w = N_NODES / 16 - 1;   // duplicate tile, same values
    const int lane = threadIdx.x & 63, lr = lane & 15, lq = lane >> 4;
    const int m0 = w * 16;
    f32x4 acc = {0.f, 0.f, 0.f, 0.f};
    for (int k0 = 0; k0 < HDIM; k0 += 32) {
        bf16x8 a = ld8(Hb + (m0 + lr) * HDIM + k0 + lq * 8);
        bf16x8 b = ld8(wot + lr * HDIM + k0 + lq * 8);
        acc = mfma16(a, b, acc);
    }
    float bias = ob[lr];
    #pragma unroll
    for (int r = 0; r < 4; ++r)
        out[Q_OFF + (m0 + lq * 4 + r) * ADIM + lr] = acc[r] + bias;
}

extern "C" void kernel_launch(void* const* d_in, const int* in_sizes, int n_in,
                              void* d_out, int out_size, void* d_ws, size_t ws_size,
                              hipStream_t stream) {
    const float* feat = (const float*)d_in[0];
    const float* h    = (const float*)d_in[1];
    const int* src    = (const int*)d_in[2];
    const int* dst    = (const int*)d_in[3];
    const float* w0   = (const float*)d_in[4];
    const float* b0   = (const float*)d_in[5];
    const float* w1   = (const float*)d_in[6];
    const float* b1   = (const float*)d_in[7];
    const float* wm   = (const float*)d_in[8];
    const float* mb   = (const float*)d_in[9];
    const float* wih  = (const float*)d_in[10];
    const float* whh  = (const float*)d_in[11];
    const float* bih  = (const float*)d_in[12];
    const float* bhh  = (const float*)d_in[13];
    const float* wo   = (const float*)d_in[14];
    const float* ob   = (const float*)d_in[15];

    char* ws = (char*)d_ws;
    unsigned short* w0t   = (unsigned short*)(ws + WS_W0T);
    unsigned short* w1t   = (unsigned short*)(ws + WS_W1T);
    unsigned short* wmt   = (unsigned short*)(ws + WS_WMT);
    unsigned short* wgt   = (unsigned short*)(ws + WS_WGT);
    unsigned short* wot   = (unsigned short*)(ws + WS_WOT);
    unsigned short* featb = (unsigned short*)(ws + WS_FEATB);
    unsigned short* hb    = (unsigned short*)(ws + WS_HB);
    unsigned short* X0    = (unsigned short*)(ws + WS_X0);
    unsigned short* X     = (unsigned short*)(ws + WS_X);
    unsigned short* Mn    = (unsigned short*)(ws + WS_MN);
    unsigned short* C     = (unsigned short*)(ws + WS_C);
    unsigned short* Hb    = (unsigned short*)(ws + WS_HNEWB);
    int* deg              = (int*)(ws + WS_DEG);
    int* off              = (int*)(ws + WS_OFF);
    int* cur              = (int*)(ws + WS_CUR);
    int* bucket           = (int*)(ws + WS_BUCKET);
    float* out            = (float*)d_out;

    hipLaunchKernelGGL(prep_kernel, dim3(1280), dim3(256), 0, stream, feat, h, featb, hb, deg);
    hipLaunchKernelGGL(transpose_weights, dim3(512), dim3(256), 0, stream,
                       w0, w1, wm, wih, whh, wo, w0t, w1t, wmt, wgt, wot);
    hipLaunchKernelGGL(hist_kernel, dim3((N_EDGES + 255) / 256), dim3(256), 0, stream, dst, deg);
    hipLaunchKernelGGL(scan_kernel, dim3(1), dim3(1024), 0, stream, deg, off, cur);
    hipLaunchKernelGGL(scatter_idx, dim3((N_EDGES + 255) / 256), dim3(256), 0, stream, src, dst, cur, bucket);
    hipLaunchKernelGGL(enc0_kernel, dim3(1252), dim3(256), 0, stream, featb, w0t, b0, X0);
    hipLaunchKernelGGL(enc1_kernel, dim3(1252), dim3(256), 0, stream, X0, w1t, b1, X);
    hipLaunchKernelGGL(msg_kernel, dim3(626), dim3(256), 0, stream, X, hb, wmt, mb, Mn);
    hipLaunchKernelGGL(aggregate_kernel, dim3((N_NODES + 3) / 4), dim3(256), 0, stream,
                       off, deg, bucket, Mn, C);
    hipLaunchKernelGGL(gru_kernel, dim3(1252), dim3(256), 0, stream,
                       X, C, hb, h, wgt, bih, bhh, Hb, out);
    hipLaunchKernelGGL(q_kernel, dim3(313), dim3(256), 0, stream, Hb, wot, ob, out);
}

// Round 6
// 328.832 us; speedup vs baseline: 4.8081x; 1.2296x over previous
//
#include <hip/hip_runtime.h>

#define N_NODES 20000
#define N_EDGES 640000
#define OBS 64
#define HDIM 256
#define MSGD 128
#define ADIM 16
#define Q_OFF 0
#define HN_OFF (N_NODES * ADIM)   // 320000

typedef __bf16 bf16x8 __attribute__((ext_vector_type(8)));
typedef float  f32x4  __attribute__((ext_vector_type(4)));

__device__ __forceinline__ unsigned short f2bf(float f) {
    union { float f; unsigned int i; } v; v.f = f;
    unsigned int i = v.i;
    return (unsigned short)((i + 0x7fffu + ((i >> 16) & 1u)) >> 16);
}
__device__ __forceinline__ float bf2f(unsigned short u) {
    union { unsigned int i; float f; } v; v.i = ((unsigned int)u) << 16; return v.f;
}
__device__ __forceinline__ bf16x8 ld8(const unsigned short* p) {
    bf16x8 r;
    __builtin_memcpy(&r, __builtin_assume_aligned(p, 16), 16);
    return r;
}
__device__ __forceinline__ f32x4 mfma16(bf16x8 a, bf16x8 b, f32x4 c) {
    return __builtin_amdgcn_mfma_f32_16x16x32_bf16(a, b, c, 0, 0, 0);
}
__device__ __forceinline__ float sigmoidf_(float x) { return 1.0f / (1.0f + __expf(-x)); }
__device__ __forceinline__ float tanhf_(float x) { return 2.0f / (1.0f + __expf(-2.0f * x)) - 1.0f; }

// fragment-packed layout: ushort index of element (row,k) in a matrix with Kc=K/32:
//   ((row>>4)*Kc + (k>>5))*512 + (((k>>3)&3)*16 + (row&15))*8 + (k&7)
// wave load of (tile,kchunk) fragment = base + (tile*Kc + c)*512 + lane*8  -> coalesced 1KB
__device__ __forceinline__ int packIdx(int row, int k, int Kc) {
    return ((row >> 4) * Kc + (k >> 5)) * 512 + (((k >> 3) & 3) * 16 + (row & 15)) * 8 + (k & 7);
}
// epilogue form: col = t*16+lr, rlow = row&15, tile = row>>4
__device__ __forceinline__ int packIdxEp(int tile, int rlow, int t, int lr, int Kc) {
    return (tile * Kc + (t >> 1)) * 512 + (((t & 1) * 2 + (lr >> 3)) * 16 + rlow) * 8 + (lr & 7);
}

// ---------------- ws layout (bytes) ----------------
#define WS_W0P    0u          // packed 256c x 64k bf16   : 32768
#define WS_W1P    32768u      // packed 256c x 256k       : 131072
#define WS_WMP    163840u     // packed 128c x 512k       : 131072
#define WS_WGP    294912u     // packed 3 x 256c x 640k   : 983040
#define WS_WOP    1277952u    // packed 16c x 256k        : 8192
#define WS_FEATP  1286144u    // packed 20000 x 64        : 2560000
#define WS_HBP    3846144u    // packed 20000 x 256       : 10240000
#define WS_X0P    14086144u   // packed 20000 x 256       : 10240000
#define WS_XP     24326144u   // packed 20000 x 256       : 10240000
#define WS_MN     34566144u   // row-major 20000 x 128    : 5120000
#define WS_CP     39686144u   // packed 20000 x 128       : 5120000
#define WS_HNP    44806144u   // packed 20000 x 256       : 10240000
#define WS_DEG    55046144u
#define WS_OFF    55126144u
#define WS_CUR    55206144u
#define WS_BUCKET 55286144u   // 640000 int (end 57846144)

#define GATE_STRIDE 163840    // ushorts per gate in wgp: 16 tiles * 20 chunks * 512

// convert fp32 feat/h into packed bf16 fragments, zero deg
__global__ __launch_bounds__(256) void prep_kernel(
    const float* __restrict__ feat, const float* __restrict__ h,
    unsigned short* __restrict__ featp, unsigned short* __restrict__ hbp,
    int* __restrict__ deg)
{
    int tid = blockIdx.x * 256 + threadIdx.x;
    int np = gridDim.x * 256;
    for (int i = tid; i < N_NODES; i += np) deg[i] = 0;
    // feat: 8-elem chunks. row = ch>>3, k = (ch&7)*8 ; coalesced 32B read, one 16B packed store
    for (int ch = tid; ch < N_NODES * OBS / 8; ch += np) {
        int row = ch >> 3, k = (ch & 7) * 8;
        const float4* p = (const float4*)(feat + row * OBS + k);
        float4 a = p[0], b = p[1];
        union { unsigned short u[8]; uint4 v; } r;
        r.u[0]=f2bf(a.x); r.u[1]=f2bf(a.y); r.u[2]=f2bf(a.z); r.u[3]=f2bf(a.w);
        r.u[4]=f2bf(b.x); r.u[5]=f2bf(b.y); r.u[6]=f2bf(b.z); r.u[7]=f2bf(b.w);
        *(uint4*)(featp + packIdx(row, k, 2)) = r.v;
    }
    // h: row = ch>>5, k = (ch&31)*8
    for (int ch = tid; ch < N_NODES * HDIM / 8; ch += np) {
        int row = ch >> 5, k = (ch & 31) * 8;
        const float4* p = (const float4*)(h + row * HDIM + k);
        float4 a = p[0], b = p[1];
        union { unsigned short u[8]; uint4 v; } r;
        r.u[0]=f2bf(a.x); r.u[1]=f2bf(a.y); r.u[2]=f2bf(a.z); r.u[3]=f2bf(a.w);
        r.u[4]=f2bf(b.x); r.u[5]=f2bf(b.y); r.u[6]=f2bf(b.z); r.u[7]=f2bf(b.w);
        *(uint4*)(hbp + packIdx(row, k, 8)) = r.v;
    }
}

// pack fp32 weights (k-major) into fragment-packed bf16 (coalesced reads, scattered 2B writes)
__global__ __launch_bounds__(256) void transpose_weights(
    const float* w0, const float* w1, const float* wm,
    const float* wih, const float* whh, const float* wo,
    unsigned short* w0p, unsigned short* w1p, unsigned short* wmp,
    unsigned short* wgp, unsigned short* wop)
{
    int tid = blockIdx.x * 256 + threadIdx.x;
    int np = gridDim.x * 256;
    for (int i = tid; i < 64 * 256; i += np)  { int k = i >> 8, n = i & 255; w0p[packIdx(n, k, 2)]  = f2bf(w0[i]); }
    for (int i = tid; i < 256 * 256; i += np) { int k = i >> 8, n = i & 255; w1p[packIdx(n, k, 8)]  = f2bf(w1[i]); }
    for (int i = tid; i < 512 * 128; i += np) { int k = i >> 7, n = i & 127; wmp[packIdx(n, k, 16)] = f2bf(wm[i]); }
    for (int i = tid; i < 384 * 768; i += np) {
        int k = i / 768, c3 = i % 768;
        int gate = c3 >> 8, col = c3 & 255;
        wgp[gate * GATE_STRIDE + packIdx(col, k, 20)] = f2bf(wih[i]);
    }
    for (int i = tid; i < 256 * 768; i += np) {
        int k = i / 768, c3 = i % 768;
        int gate = c3 >> 8, col = c3 & 255;
        wgp[gate * GATE_STRIDE + packIdx(col, 384 + k, 20)] = f2bf(whh[i]);
    }
    for (int i = tid; i < 256 * 16; i += np)  { int k = i >> 4, n = i & 15; wop[packIdx(n, k, 8)] = f2bf(wo[i]); }
}

__global__ __launch_bounds__(256) void hist_kernel(const int* __restrict__ dst, int* __restrict__ deg) {
    int i = blockIdx.x * 256 + threadIdx.x;
    if (i < N_EDGES) atomicAdd(&deg[dst[i]], 1);
}

__global__ __launch_bounds__(1024) void scan_kernel(const int* __restrict__ deg,
                                                    int* __restrict__ off, int* __restrict__ cur) {
    __shared__ int part[1024];
    const int t = threadIdx.x;
    const int base = t * 20;
    int s = 0;
    #pragma unroll
    for (int i = 0; i < 20; ++i) { int idx = base + i; if (idx < N_NODES) s += deg[idx]; }
    part[t] = s;
    __syncthreads();
    int acc = s;
    for (int d = 1; d < 1024; d <<= 1) {
        int v = (t >= d) ? part[t - d] : 0;
        __syncthreads();
        acc += v; part[t] = acc;
        __syncthreads();
    }
    int run = acc - s;
    for (int i = 0; i < 20; ++i) {
        int idx = base + i;
        if (idx < N_NODES) { off[idx] = run; cur[idx] = run; run += deg[idx]; }
    }
}

__global__ __launch_bounds__(256) void scatter_idx(const int* __restrict__ src, const int* __restrict__ dst,
                                                   int* __restrict__ cur, int* __restrict__ bucket) {
    int i = blockIdx.x * 256 + threadIdx.x;
    if (i < N_EDGES) {
        int d = dst[i];
        int pos = atomicAdd(&cur[d], 1);
        bucket[pos] = src[i];
    }
}

// enc0: X0 = relu(feat @ W0 + b0). wave=(m64, coltile of 256). 313*16 waves.
__global__ __launch_bounds__(256) void enc0_kernel(
    const unsigned short* __restrict__ featp, const unsigned short* __restrict__ w0p,
    const float* __restrict__ b0, unsigned short* __restrict__ X0p)
{
    const int w = blockIdx.x * 4 + (threadIdx.x >> 6);
    const int lane = threadIdx.x & 63, lr = lane & 15, lq = lane >> 4;
    const int m64 = w >> 4, t = w & 15;
    int tA[4]; bool val[4];
    #pragma unroll
    for (int mf = 0; mf < 4; ++mf) { int tl = m64 * 4 + mf; val[mf] = tl < 1250; tA[mf] = val[mf] ? tl : 1249; }
    f32x4 acc[4] = {{0,0,0,0},{0,0,0,0},{0,0,0,0},{0,0,0,0}};
    #pragma unroll
    for (int c = 0; c < 2; ++c) {
        bf16x8 b = ld8(w0p + (t * 2 + c) * 512 + lane * 8);
        #pragma unroll
        for (int mf = 0; mf < 4; ++mf) {
            bf16x8 a = ld8(featp + (tA[mf] * 2 + c) * 512 + lane * 8);
            acc[mf] = mfma16(a, b, acc[mf]);
        }
    }
    float bias = b0[t * 16 + lr];
    #pragma unroll
    for (int mf = 0; mf < 4; ++mf) if (val[mf])
        #pragma unroll
        for (int r = 0; r < 4; ++r)
            X0p[packIdxEp(tA[mf], lq * 4 + r, t, lr, 8)] = f2bf(fmaxf(acc[mf][r] + bias, 0.f));
}

// enc1: X = relu(X0 @ W1 + b1). 313*16 waves.
__global__ __launch_bounds__(256) void enc1_kernel(
    const unsigned short* __restrict__ X0p, const unsigned short* __restrict__ w1p,
    const float* __restrict__ b1, unsigned short* __restrict__ Xp)
{
    const int w = blockIdx.x * 4 + (threadIdx.x >> 6);
    const int lane = threadIdx.x & 63, lr = lane & 15, lq = lane >> 4;
    const int m64 = w >> 4, t = w & 15;
    int tA[4]; bool val[4];
    #pragma unroll
    for (int mf = 0; mf < 4; ++mf) { int tl = m64 * 4 + mf; val[mf] = tl < 1250; tA[mf] = val[mf] ? tl : 1249; }
    f32x4 acc[4] = {{0,0,0,0},{0,0,0,0},{0,0,0,0},{0,0,0,0}};
    for (int c = 0; c < 8; ++c) {
        bf16x8 b = ld8(w1p + (t * 8 + c) * 512 + lane * 8);
        #pragma unroll
        for (int mf = 0; mf < 4; ++mf) {
            bf16x8 a = ld8(X0p + (tA[mf] * 8 + c) * 512 + lane * 8);
            acc[mf] = mfma16(a, b, acc[mf]);
        }
    }
    float bias = b1[t * 16 + lr];
    #pragma unroll
    for (int mf = 0; mf < 4; ++mf) if (val[mf])
        #pragma unroll
        for (int r = 0; r < 4; ++r)
            Xp[packIdxEp(tA[mf], lq * 4 + r, t, lr, 8)] = f2bf(fmaxf(acc[mf][r] + bias, 0.f));
}

// msg: Mnode = X @ Wx + h @ Wh + mb -> row-major (for aggregate). 313*8 waves.
__global__ __launch_bounds__(256) void msg_kernel(
    const unsigned short* __restrict__ Xp, const unsigned short* __restrict__ hbp,
    const unsigned short* __restrict__ wmp, const float* __restrict__ mb,
    unsigned short* __restrict__ Mn)
{
    const int w = blockIdx.x * 4 + (threadIdx.x >> 6);
    const int lane = threadIdx.x & 63, lr = lane & 15, lq = lane >> 4;
    const int m64 = w >> 3, t = w & 7;
    const int col = t * 16 + lr;
    int tA[4]; bool val[4];
    #pragma unroll
    for (int mf = 0; mf < 4; ++mf) { int tl = m64 * 4 + mf; val[mf] = tl < 1250; tA[mf] = val[mf] ? tl : 1249; }
    f32x4 acc[4] = {{0,0,0,0},{0,0,0,0},{0,0,0,0},{0,0,0,0}};
    for (int c = 0; c < 8; ++c) {            // X part (k 0..255)
        bf16x8 b = ld8(wmp + (t * 16 + c) * 512 + lane * 8);
        #pragma unroll
        for (int mf = 0; mf < 4; ++mf) {
            bf16x8 a = ld8(Xp + (tA[mf] * 8 + c) * 512 + lane * 8);
            acc[mf] = mfma16(a, b, acc[mf]);
        }
    }
    for (int c = 0; c < 8; ++c) {            // h part (k 256..511)
        bf16x8 b = ld8(wmp + (t * 16 + 8 + c) * 512 + lane * 8);
        #pragma unroll
        for (int mf = 0; mf < 4; ++mf) {
            bf16x8 a = ld8(hbp + (tA[mf] * 8 + c) * 512 + lane * 8);
            acc[mf] = mfma16(a, b, acc[mf]);
        }
    }
    float bias = mb[col];
    #pragma unroll
    for (int mf = 0; mf < 4; ++mf) if (val[mf])
        #pragma unroll
        for (int r = 0; r < 4; ++r) {
            int row = m64 * 64 + mf * 16 + lq * 4 + r;
            Mn[row * MSGD + col] = f2bf(acc[mf][r] + bias);
        }
}

// one wave per node: gather Mn rows, mean, write packed C row (one 4B store/lane).
__global__ __launch_bounds__(256) void aggregate_kernel(
    const int* __restrict__ off, const int* __restrict__ deg,
    const int* __restrict__ bucket, const unsigned short* __restrict__ Mn,
    unsigned short* __restrict__ Cp)
{
    const int wave = threadIdx.x >> 6;
    const int lane = threadIdx.x & 63;
    const int node = blockIdx.x * 4 + wave;
    if (node >= N_NODES) return;
    const int o = off[node], dg = deg[node];
    float s0 = 0.f, s1 = 0.f;
    const unsigned int* mn = (const unsigned int*)Mn;
    int j = 0;
    for (; j + 4 <= dg; j += 4) {
        int i0 = bucket[o + j], i1 = bucket[o + j + 1], i2 = bucket[o + j + 2], i3 = bucket[o + j + 3];
        unsigned int p0 = mn[i0 * 64 + lane], p1 = mn[i1 * 64 + lane];
        unsigned int p2 = mn[i2 * 64 + lane], p3 = mn[i3 * 64 + lane];
        s0 += bf2f((unsigned short)(p0 & 0xffffu)) + bf2f((unsigned short)(p1 & 0xffffu))
            + bf2f((unsigned short)(p2 & 0xffffu)) + bf2f((unsigned short)(p3 & 0xffffu));
        s1 += bf2f((unsigned short)(p0 >> 16)) + bf2f((unsigned short)(p1 >> 16))
            + bf2f((unsigned short)(p2 >> 16)) + bf2f((unsigned short)(p3 >> 16));
    }
    for (; j < dg; ++j) {
        int sidx = bucket[o + j];
        unsigned int pk = mn[sidx * 64 + lane];
        s0 += bf2f((unsigned short)(pk & 0xffffu));
        s1 += bf2f((unsigned short)(pk >> 16));
    }
    float invc = 1.0f / fmaxf((float)dg, 1.0f);
    unsigned int outpk = ((unsigned int)f2bf(s1 * invc) << 16) | (unsigned int)f2bf(s0 * invc);
    int k0 = 2 * lane;   // k0 even -> (k0&7) even -> 4B-aligned packed pair
    int idx = packIdx(node, k0, 4);
    *(unsigned int*)(Cp + idx) = outpk;
}

// GRU gates + h_new. wave=(m64, coltile of 256). K=640 = [X 256 | C 128 | h 256]. 313*16 waves.
__global__ __launch_bounds__(256) void gru_kernel(
    const unsigned short* __restrict__ Xp, const unsigned short* __restrict__ Cp,
    const unsigned short* __restrict__ hbp, const float* __restrict__ h,
    const unsigned short* __restrict__ wgp,
    const float* __restrict__ bih, const float* __restrict__ bhh,
    unsigned short* __restrict__ Hnp, float* __restrict__ out)
{
    const int w = blockIdx.x * 4 + (threadIdx.x >> 6);
    const int lane = threadIdx.x & 63, lr = lane & 15, lq = lane >> 4;
    const int m64 = w >> 4, t = w & 15;
    const int col = t * 16 + lr;
    int tA[4]; bool val[4];
    #pragma unroll
    for (int mf = 0; mf < 4; ++mf) { int tl = m64 * 4 + mf; val[mf] = tl < 1250; tA[mf] = val[mf] ? tl : 1249; }

    f32x4 ar[4]  = {{0,0,0,0},{0,0,0,0},{0,0,0,0},{0,0,0,0}};
    f32x4 az[4]  = {{0,0,0,0},{0,0,0,0},{0,0,0,0},{0,0,0,0}};
    f32x4 ani[4] = {{0,0,0,0},{0,0,0,0},{0,0,0,0},{0,0,0,0}};
    f32x4 anh[4] = {{0,0,0,0},{0,0,0,0},{0,0,0,0},{0,0,0,0}};

    const unsigned short* wr = wgp + 0 * GATE_STRIDE + t * 20 * 512 + lane * 8;
    const unsigned short* wz = wgp + 1 * GATE_STRIDE + t * 20 * 512 + lane * 8;
    const unsigned short* wn = wgp + 2 * GATE_STRIDE + t * 20 * 512 + lane * 8;

    for (int c = 0; c < 8; ++c) {        // X part: chunks 0..7
        bf16x8 br = ld8(wr + c * 512);
        bf16x8 bz = ld8(wz + c * 512);
        bf16x8 bn = ld8(wn + c * 512);
        #pragma unroll
        for (int mf = 0; mf < 4; ++mf) {
            bf16x8 a = ld8(Xp + (tA[mf] * 8 + c) * 512 + lane * 8);
            ar[mf]  = mfma16(a, br, ar[mf]);
            az[mf]  = mfma16(a, bz, az[mf]);
            ani[mf] = mfma16(a, bn, ani[mf]);
        }
    }
    for (int c = 0; c < 4; ++c) {        // C part: chunks 8..11
        bf16x8 br = ld8(wr + (8 + c) * 512);
        bf16x8 bz = ld8(wz + (8 + c) * 512);
        bf16x8 bn = ld8(wn + (8 + c) * 512);
        #pragma unroll
        for (int mf = 0; mf < 4; ++mf) {
            bf16x8 a = ld8(Cp + (tA[mf] * 4 + c) * 512 + lane * 8);
            ar[mf]  = mfma16(a, br, ar[mf]);
            az[mf]  = mfma16(a, bz, az[mf]);
            ani[mf] = mfma16(a, bn, ani[mf]);
        }
    }
    for (int c = 0; c < 8; ++c) {        // h part: chunks 12..19; n-gate separate
        bf16x8 br = ld8(wr + (12 + c) * 512);
        bf16x8 bz = ld8(wz + (12 + c) * 512);
        bf16x8 bn = ld8(wn + (12 + c) * 512);
        #pragma unroll
        for (int mf = 0; mf < 4; ++mf) {
            bf16x8 a = ld8(hbp + (tA[mf] * 8 + c) * 512 + lane * 8);
            ar[mf]  = mfma16(a, br, ar[mf]);
            az[mf]  = mfma16(a, bz, az[mf]);
            anh[mf] = mfma16(a, bn, anh[mf]);
        }
    }

    const float bir = bih[col] + bhh[col];
    const float biz = bih[256 + col] + bhh[256 + col];
    const float bin = bih[512 + col];
    const float bhn = bhh[512 + col];
    #pragma unroll
    for (int mf = 0; mf < 4; ++mf) if (val[mf])
        #pragma unroll
        for (int r = 0; r < 4; ++r) {
            int row = m64 * 64 + mf * 16 + lq * 4 + r;
            float rg = sigmoidf_(ar[mf][r] + bir);
            float zg = sigmoidf_(az[mf][r] + biz);
            float ng = tanhf_(ani[mf][r] + bin + rg * (anh[mf][r] + bhn));
            float ho = h[row * HDIM + col];
            float hn = (1.0f - zg) * ng + zg * ho;
            out[HN_OFF + row * HDIM + col] = hn;
            Hnp[packIdxEp(tA[mf], lq * 4 + r, t, lr, 8)] = f2bf(hn);
        }
}

// q = h_new @ out_W + out_b. one wave per 16-row tile.
__global__ __launch_bounds__(256) void q_kernel(
    const unsigned short* __restrict__ Hnp, const unsigned short* __restrict__ wop,
    const float* __restrict__ ob, float* __restrict__ out)
{
    int w = blockIdx.x * 4 + (threadIdx.x >> 6);
    if (w >= 1250) w = 1249;   // duplicate tile, same values
    const int lane = threadIdx.x & 63, lr = lane & 15, lq = lane >> 4;
    f32x4 acc = {0.f, 0.f, 0.f, 0.f};
    for (int c = 0; c < 8; ++c) {
        bf16x8 a = ld8(Hnp + (w * 8 + c) * 512 + lane * 8);
        bf16x8 b = ld8(wop + c * 512 + lane * 8);
        acc = mfma16(a, b, acc);
    }
    float bias = ob[lr];
    #pragma unroll
    for (int r = 0; r < 4; ++r)
        out[Q_OFF + (w * 16 + lq * 4 + r) * ADIM + lr] = acc[r] + bias;
}

extern "C" void kernel_launch(void* const* d_in, const int* in_sizes, int n_in,
                              void* d_out, int out_size, void* d_ws, size_t ws_size,
                              hipStream_t stream) {
    const float* feat = (const float*)d_in[0];
    const float* h    = (const float*)d_in[1];
    const int* src    = (const int*)d_in[2];
    const int* dst    = (const int*)d_in[3];
    const float* w0   = (const float*)d_in[4];
    const float* b0   = (const float*)d_in[5];
    const float* w1   = (const float*)d_in[6];
    const float* b1   = (const float*)d_in[7];
    const float* wm   = (const float*)d_in[8];
    const float* mb   = (const float*)d_in[9];
    const float* wih  = (const float*)d_in[10];
    const float* whh  = (const float*)d_in[11];
    const float* bih  = (const float*)d_in[12];
    const float* bhh  = (const float*)d_in[13];
    const float* wo   = (const float*)d_in[14];
    const float* ob   = (const float*)d_in[15];

    char* ws = (char*)d_ws;
    unsigned short* w0p   = (unsigned short*)(ws + WS_W0P);
    unsigned short* w1p   = (unsigned short*)(ws + WS_W1P);
    unsigned short* wmp   = (unsigned short*)(ws + WS_WMP);
    unsigned short* wgp   = (unsigned short*)(ws + WS_WGP);
    unsigned short* wop   = (unsigned short*)(ws + WS_WOP);
    unsigned short* featp = (unsigned short*)(ws + WS_FEATP);
    unsigned short* hbp   = (unsigned short*)(ws + WS_HBP);
    unsigned short* X0p   = (unsigned short*)(ws + WS_X0P);
    unsigned short* Xp    = (unsigned short*)(ws + WS_XP);
    unsigned short* Mn    = (unsigned short*)(ws + WS_MN);
    unsigned short* Cp    = (unsigned short*)(ws + WS_CP);
    unsigned short* Hnp   = (unsigned short*)(ws + WS_HNP);
    int* deg              = (int*)(ws + WS_DEG);
    int* off              = (int*)(ws + WS_OFF);
    int* cur              = (int*)(ws + WS_CUR);
    int* bucket           = (int*)(ws + WS_BUCKET);
    float* out            = (float*)d_out;

    hipLaunchKernelGGL(prep_kernel, dim3(1280), dim3(256), 0, stream, feat, h, featp, hbp, deg);
    hipLaunchKernelGGL(transpose_weights, dim3(512), dim3(256), 0, stream,
                       w0, w1, wm, wih, whh, wo, w0p, w1p, wmp, wgp, wop);
    hipLaunchKernelGGL(hist_kernel, dim3((N_EDGES + 255) / 256), dim3(256), 0, stream, dst, deg);
    hipLaunchKernelGGL(scan_kernel, dim3(1), dim3(1024), 0, stream, deg, off, cur);
    hipLaunchKernelGGL(scatter_idx, dim3((N_EDGES + 255) / 256), dim3(256), 0, stream, src, dst, cur, bucket);
    hipLaunchKernelGGL(enc0_kernel, dim3(1252), dim3(256), 0, stream, featp, w0p, b0, X0p);
    hipLaunchKernelGGL(enc1_kernel, dim3(1252), dim3(256), 0, stream, X0p, w1p, b1, Xp);
    hipLaunchKernelGGL(msg_kernel, dim3(626), dim3(256), 0, stream, Xp, hbp, wmp, mb, Mn);
    hipLaunchKernelGGL(aggregate_kernel, dim3((N_NODES + 3) / 4), dim3(256), 0, stream,
                       off, deg, bucket, Mn, Cp);
    hipLaunchKernelGGL(gru_kernel, dim3(1252), dim3(256), 0, stream,
                       Xp, Cp, hbp, h, wgp, bih, bhh, Hnp, out);
    hipLaunchKernelGGL(q_kernel, dim3(313), dim3(256), 0, stream, Hnp, wop, ob, out);
}

// Round 7
// 311.871 us; speedup vs baseline: 5.0696x; 1.0544x over previous
//
#include <hip/hip_runtime.h>

#define N_NODES 20000
#define N_EDGES 640000
#define OBS 64
#define HDIM 256
#define MSGD 128
#define ADIM 16
#define Q_OFF 0
#define HN_OFF (N_NODES * ADIM)   // 320000

typedef __bf16 bf16x8 __attribute__((ext_vector_type(8)));
typedef float  f32x4  __attribute__((ext_vector_type(4)));

__device__ __forceinline__ unsigned short f2bf(float f) {
    union { float f; unsigned int i; } v; v.f = f;
    unsigned int i = v.i;
    return (unsigned short)((i + 0x7fffu + ((i >> 16) & 1u)) >> 16);
}
__device__ __forceinline__ float bf2f(unsigned short u) {
    union { unsigned int i; float f; } v; v.i = ((unsigned int)u) << 16; return v.f;
}
__device__ __forceinline__ bf16x8 ld8(const unsigned short* p) {
    bf16x8 r;
    __builtin_memcpy(&r, __builtin_assume_aligned(p, 16), 16);
    return r;
}
__device__ __forceinline__ f32x4 mfma16(bf16x8 a, bf16x8 b, f32x4 c) {
    return __builtin_amdgcn_mfma_f32_16x16x32_bf16(a, b, c, 0, 0, 0);
}
__device__ __forceinline__ float sigmoidf_(float x) { return 1.0f / (1.0f + __expf(-x)); }
__device__ __forceinline__ float tanhf_(float x) { return 2.0f / (1.0f + __expf(-2.0f * x)) - 1.0f; }

// fragment-packed layout: element (row,k) of a K-major matrix, Kc=K/32:
//   ((row>>4)*Kc + (k>>5))*512 + (((k>>3)&3)*16 + (row&15))*8 + (k&7)
__device__ __forceinline__ int packIdx(int row, int k, int Kc) {
    return ((row >> 4) * Kc + (k >> 5)) * 512 + (((k >> 3) & 3) * 16 + (row & 15)) * 8 + (k & 7);
}
__device__ __forceinline__ int packIdxEp(int tile, int rlow, int t, int lr, int Kc) {
    return (tile * Kc + (t >> 1)) * 512 + (((t & 1) * 2 + (lr >> 3)) * 16 + rlow) * 8 + (lr & 7);
}

// ---------------- ws layout (bytes) ----------------
#define WS_W0P    0u          // packed 256c x 64k bf16
#define WS_W1P    32768u      // packed 256c x 256k
#define WS_WMP    163840u     // packed 128c x 512k
#define WS_WGP    294912u     // packed 3 x 256c x 640k
#define WS_WOP    1277952u    // packed 16c x 256k
#define WS_FEATP  1286144u    // packed 20000 x 64
#define WS_HBP    3846144u    // packed 20000 x 256
#define WS_X0P    14086144u   // packed 20000 x 256
#define WS_XP     24326144u   // packed 20000 x 256
#define WS_MN     34566144u   // row-major 20000 x 128
#define WS_CP     39686144u   // packed 20000 x 128
#define WS_HNP    44806144u   // packed 20000 x 256
#define WS_DEG    55046144u
#define WS_OFF    55126144u
#define WS_CUR    55206144u
#define WS_BUCKET 55286144u   // 640000 int
#define WS_HBROW  57846144u   // row-major 20000 x 256 bf16 (end 68086144)

#define GATE_STRIDE 163840

// fused setup: feat/h -> bf16 (packed + row-major h), weight packing, dst histogram.
// deg must be zeroed (memsetAsync) before this launches.
__global__ __launch_bounds__(256) void setup_kernel(
    const float* __restrict__ feat, const float* __restrict__ h,
    const float* __restrict__ w0, const float* __restrict__ w1, const float* __restrict__ wm,
    const float* __restrict__ wih, const float* __restrict__ whh, const float* __restrict__ wo,
    const int* __restrict__ dst,
    unsigned short* __restrict__ featp, unsigned short* __restrict__ hbp,
    unsigned short* __restrict__ hbrow,
    unsigned short* __restrict__ w0p, unsigned short* __restrict__ w1p,
    unsigned short* __restrict__ wmp, unsigned short* __restrict__ wgp,
    unsigned short* __restrict__ wop, int* __restrict__ deg)
{
    int tid = blockIdx.x * 256 + threadIdx.x;
    int np = gridDim.x * 256;
    for (int ch = tid; ch < N_NODES * OBS / 8; ch += np) {
        int row = ch >> 3, k = (ch & 7) * 8;
        const float4* p = (const float4*)(feat + row * OBS + k);
        float4 a = p[0], b = p[1];
        union { unsigned short u[8]; uint4 v; } r;
        r.u[0]=f2bf(a.x); r.u[1]=f2bf(a.y); r.u[2]=f2bf(a.z); r.u[3]=f2bf(a.w);
        r.u[4]=f2bf(b.x); r.u[5]=f2bf(b.y); r.u[6]=f2bf(b.z); r.u[7]=f2bf(b.w);
        *(uint4*)(featp + packIdx(row, k, 2)) = r.v;
    }
    for (int ch = tid; ch < N_NODES * HDIM / 8; ch += np) {
        int row = ch >> 5, k = (ch & 31) * 8;
        const float4* p = (const float4*)(h + row * HDIM + k);
        float4 a = p[0], b = p[1];
        union { unsigned short u[8]; uint4 v; } r;
        r.u[0]=f2bf(a.x); r.u[1]=f2bf(a.y); r.u[2]=f2bf(a.z); r.u[3]=f2bf(a.w);
        r.u[4]=f2bf(b.x); r.u[5]=f2bf(b.y); r.u[6]=f2bf(b.z); r.u[7]=f2bf(b.w);
        *(uint4*)(hbp + packIdx(row, k, 8)) = r.v;
        *(uint4*)(hbrow + row * HDIM + k) = r.v;
    }
    for (int i = tid; i < 64 * 256; i += np)  { int k = i >> 8, n = i & 255; w0p[packIdx(n, k, 2)]  = f2bf(w0[i]); }
    for (int i = tid; i < 256 * 256; i += np) { int k = i >> 8, n = i & 255; w1p[packIdx(n, k, 8)]  = f2bf(w1[i]); }
    for (int i = tid; i < 512 * 128; i += np) { int k = i >> 7, n = i & 127; wmp[packIdx(n, k, 16)] = f2bf(wm[i]); }
    for (int i = tid; i < 384 * 768; i += np) {
        int k = i / 768, c3 = i % 768;
        wgp[(c3 >> 8) * GATE_STRIDE + packIdx(c3 & 255, k, 20)] = f2bf(wih[i]);
    }
    for (int i = tid; i < 256 * 768; i += np) {
        int k = i / 768, c3 = i % 768;
        wgp[(c3 >> 8) * GATE_STRIDE + packIdx(c3 & 255, 384 + k, 20)] = f2bf(whh[i]);
    }
    for (int i = tid; i < 256 * 16; i += np)  { int k = i >> 4, n = i & 15; wop[packIdx(n, k, 8)] = f2bf(wo[i]); }
    for (int i = tid; i < N_EDGES; i += np) atomicAdd(&deg[dst[i]], 1);
}

__global__ __launch_bounds__(1024) void scan_kernel(const int* __restrict__ deg,
                                                    int* __restrict__ off, int* __restrict__ cur) {
    __shared__ int part[1024];
    const int t = threadIdx.x;
    const int base = t * 20;
    int s = 0;
    #pragma unroll
    for (int i = 0; i < 20; ++i) { int idx = base + i; if (idx < N_NODES) s += deg[idx]; }
    part[t] = s;
    __syncthreads();
    int acc = s;
    for (int d = 1; d < 1024; d <<= 1) {
        int v = (t >= d) ? part[t - d] : 0;
        __syncthreads();
        acc += v; part[t] = acc;
        __syncthreads();
    }
    int run = acc - s;
    for (int i = 0; i < 20; ++i) {
        int idx = base + i;
        if (idx < N_NODES) { off[idx] = run; cur[idx] = run; run += deg[idx]; }
    }
}

__global__ __launch_bounds__(256) void scatter_idx(const int* __restrict__ src, const int* __restrict__ dst,
                                                   int* __restrict__ cur, int* __restrict__ bucket) {
    int i = blockIdx.x * 256 + threadIdx.x;
    if (i < N_EDGES) {
        int d = dst[i];
        int pos = atomicAdd(&cur[d], 1);
        bucket[pos] = src[i];
    }
}

// enc0: X0 = relu(feat @ W0 + b0). 313*16 waves.
__global__ __launch_bounds__(256) void enc0_kernel(
    const unsigned short* __restrict__ featp, const unsigned short* __restrict__ w0p,
    const float* __restrict__ b0, unsigned short* __restrict__ X0p)
{
    const int w = blockIdx.x * 4 + (threadIdx.x >> 6);
    const int lane = threadIdx.x & 63, lr = lane & 15, lq = lane >> 4;
    const int m64 = w >> 4, t = w & 15;
    int tA[4]; bool val[4];
    #pragma unroll
    for (int mf = 0; mf < 4; ++mf) { int tl = m64 * 4 + mf; val[mf] = tl < 1250; tA[mf] = val[mf] ? tl : 1249; }
    f32x4 acc[4] = {{0,0,0,0},{0,0,0,0},{0,0,0,0},{0,0,0,0}};
    #pragma unroll
    for (int c = 0; c < 2; ++c) {
        bf16x8 b = ld8(w0p + (t * 2 + c) * 512 + lane * 8);
        #pragma unroll
        for (int mf = 0; mf < 4; ++mf) {
            bf16x8 a = ld8(featp + (tA[mf] * 2 + c) * 512 + lane * 8);
            acc[mf] = mfma16(a, b, acc[mf]);
        }
    }
    float bias = b0[t * 16 + lr];
    #pragma unroll
    for (int mf = 0; mf < 4; ++mf) if (val[mf])
        #pragma unroll
        for (int r = 0; r < 4; ++r)
            X0p[packIdxEp(tA[mf], lq * 4 + r, t, lr, 8)] = f2bf(fmaxf(acc[mf][r] + bias, 0.f));
}

// enc1: X = relu(X0 @ W1 + b1). 313*16 waves.
__global__ __launch_bounds__(256) void enc1_kernel(
    const unsigned short* __restrict__ X0p, const unsigned short* __restrict__ w1p,
    const float* __restrict__ b1, unsigned short* __restrict__ Xp)
{
    const int w = blockIdx.x * 4 + (threadIdx.x >> 6);
    const int lane = threadIdx.x & 63, lr = lane & 15, lq = lane >> 4;
    const int m64 = w >> 4, t = w & 15;
    int tA[4]; bool val[4];
    #pragma unroll
    for (int mf = 0; mf < 4; ++mf) { int tl = m64 * 4 + mf; val[mf] = tl < 1250; tA[mf] = val[mf] ? tl : 1249; }
    f32x4 acc[4] = {{0,0,0,0},{0,0,0,0},{0,0,0,0},{0,0,0,0}};
    #pragma unroll
    for (int c = 0; c < 8; ++c) {
        bf16x8 b = ld8(w1p + (t * 8 + c) * 512 + lane * 8);
        #pragma unroll
        for (int mf = 0; mf < 4; ++mf) {
            bf16x8 a = ld8(X0p + (tA[mf] * 8 + c) * 512 + lane * 8);
            acc[mf] = mfma16(a, b, acc[mf]);
        }
    }
    float bias = b1[t * 16 + lr];
    #pragma unroll
    for (int mf = 0; mf < 4; ++mf) if (val[mf])
        #pragma unroll
        for (int r = 0; r < 4; ++r)
            Xp[packIdxEp(tA[mf], lq * 4 + r, t, lr, 8)] = f2bf(fmaxf(acc[mf][r] + bias, 0.f));
}

// msg: Mnode = X @ Wx + h @ Wh + mb -> row-major. 313*8 waves.
__global__ __launch_bounds__(256) void msg_kernel(
    const unsigned short* __restrict__ Xp, const unsigned short* __restrict__ hbp,
    const unsigned short* __restrict__ wmp, const float* __restrict__ mb,
    unsigned short* __restrict__ Mn)
{
    const int w = blockIdx.x * 4 + (threadIdx.x >> 6);
    const int lane = threadIdx.x & 63, lr = lane & 15, lq = lane >> 4;
    const int m64 = w >> 3, t = w & 7;
    const int col = t * 16 + lr;
    int tA[4]; bool val[4];
    #pragma unroll
    for (int mf = 0; mf < 4; ++mf) { int tl = m64 * 4 + mf; val[mf] = tl < 1250; tA[mf] = val[mf] ? tl : 1249; }
    f32x4 acc[4] = {{0,0,0,0},{0,0,0,0},{0,0,0,0},{0,0,0,0}};
    #pragma unroll 4
    for (int c = 0; c < 8; ++c) {
        bf16x8 b = ld8(wmp + (t * 16 + c) * 512 + lane * 8);
        #pragma unroll
        for (int mf = 0; mf < 4; ++mf) {
            bf16x8 a = ld8(Xp + (tA[mf] * 8 + c) * 512 + lane * 8);
            acc[mf] = mfma16(a, b, acc[mf]);
        }
    }
    #pragma unroll 4
    for (int c = 0; c < 8; ++c) {
        bf16x8 b = ld8(wmp + (t * 16 + 8 + c) * 512 + lane * 8);
        #pragma unroll
        for (int mf = 0; mf < 4; ++mf) {
            bf16x8 a = ld8(hbp + (tA[mf] * 8 + c) * 512 + lane * 8);
            acc[mf] = mfma16(a, b, acc[mf]);
        }
    }
    float bias = mb[col];
    #pragma unroll
    for (int mf = 0; mf < 4; ++mf) if (val[mf])
        #pragma unroll
        for (int r = 0; r < 4; ++r) {
            int row = m64 * 64 + mf * 16 + lq * 4 + r;
            Mn[row * MSGD + col] = f2bf(acc[mf][r] + bias);
        }
}

// one wave per node: gather Mn rows, mean, write packed C row.
__global__ __launch_bounds__(256) void aggregate_kernel(
    const int* __restrict__ off, const int* __restrict__ deg,
    const int* __restrict__ bucket, const unsigned short* __restrict__ Mn,
    unsigned short* __restrict__ Cp)
{
    const int wave = threadIdx.x >> 6;
    const int lane = threadIdx.x & 63;
    const int node = blockIdx.x * 4 + wave;
    if (node >= N_NODES) return;
    const int o = off[node], dg = deg[node];
    float s0 = 0.f, s1 = 0.f;
    const unsigned int* mn = (const unsigned int*)Mn;
    int j = 0;
    for (; j + 4 <= dg; j += 4) {
        int i0 = bucket[o + j], i1 = bucket[o + j + 1], i2 = bucket[o + j + 2], i3 = bucket[o + j + 3];
        unsigned int p0 = mn[i0 * 64 + lane], p1 = mn[i1 * 64 + lane];
        unsigned int p2 = mn[i2 * 64 + lane], p3 = mn[i3 * 64 + lane];
        s0 += bf2f((unsigned short)(p0 & 0xffffu)) + bf2f((unsigned short)(p1 & 0xffffu))
            + bf2f((unsigned short)(p2 & 0xffffu)) + bf2f((unsigned short)(p3 & 0xffffu));
        s1 += bf2f((unsigned short)(p0 >> 16)) + bf2f((unsigned short)(p1 >> 16))
            + bf2f((unsigned short)(p2 >> 16)) + bf2f((unsigned short)(p3 >> 16));
    }
    for (; j < dg; ++j) {
        int sidx = bucket[o + j];
        unsigned int pk = mn[sidx * 64 + lane];
        s0 += bf2f((unsigned short)(pk & 0xffffu));
        s1 += bf2f((unsigned short)(pk >> 16));
    }
    float invc = 1.0f / fmaxf((float)dg, 1.0f);
    unsigned int outpk = ((unsigned int)f2bf(s1 * invc) << 16) | (unsigned int)f2bf(s0 * invc);
    *(unsigned int*)(Cp + packIdx(node, 2 * lane, 4)) = outpk;
}

// GRU gates + h_new. K=640 = [X 256 | C 128 | h 256]. 313*16 waves.
__global__ __launch_bounds__(256) void gru_kernel(
    const unsigned short* __restrict__ Xp, const unsigned short* __restrict__ Cp,
    const unsigned short* __restrict__ hbp, const unsigned short* __restrict__ hbrow,
    const unsigned short* __restrict__ wgp,
    const float* __restrict__ bih, const float* __restrict__ bhh,
    unsigned short* __restrict__ Hnp, float* __restrict__ out)
{
    const int w = blockIdx.x * 4 + (threadIdx.x >> 6);
    const int lane = threadIdx.x & 63, lr = lane & 15, lq = lane >> 4;
    const int m64 = w >> 4, t = w & 15;
    const int col = t * 16 + lr;
    int tA[4]; bool val[4];
    #pragma unroll
    for (int mf = 0; mf < 4; ++mf) { int tl = m64 * 4 + mf; val[mf] = tl < 1250; tA[mf] = val[mf] ? tl : 1249; }

    f32x4 ar[4]  = {{0,0,0,0},{0,0,0,0},{0,0,0,0},{0,0,0,0}};
    f32x4 az[4]  = {{0,0,0,0},{0,0,0,0},{0,0,0,0},{0,0,0,0}};
    f32x4 ani[4] = {{0,0,0,0},{0,0,0,0},{0,0,0,0},{0,0,0,0}};
    f32x4 anh[4] = {{0,0,0,0},{0,0,0,0},{0,0,0,0},{0,0,0,0}};

    const unsigned short* wr = wgp + 0 * GATE_STRIDE + t * 20 * 512 + lane * 8;
    const unsigned short* wz = wgp + 1 * GATE_STRIDE + t * 20 * 512 + lane * 8;
    const unsigned short* wn = wgp + 2 * GATE_STRIDE + t * 20 * 512 + lane * 8;

    #pragma unroll 2
    for (int c = 0; c < 8; ++c) {        // X part
        bf16x8 br = ld8(wr + c * 512);
        bf16x8 bz = ld8(wz + c * 512);
        bf16x8 bn = ld8(wn + c * 512);
        #pragma unroll
        for (int mf = 0; mf < 4; ++mf) {
            bf16x8 a = ld8(Xp + (tA[mf] * 8 + c) * 512 + lane * 8);
            ar[mf]  = mfma16(a, br, ar[mf]);
            az[mf]  = mfma16(a, bz, az[mf]);
            ani[mf] = mfma16(a, bn, ani[mf]);
        }
    }
    #pragma unroll 2
    for (int c = 0; c < 4; ++c) {        // C part
        bf16x8 br = ld8(wr + (8 + c) * 512);
        bf16x8 bz = ld8(wz + (8 + c) * 512);
        bf16x8 bn = ld8(wn + (8 + c) * 512);
        #pragma unroll
        for (int mf = 0; mf < 4; ++mf) {
            bf16x8 a = ld8(Cp + (tA[mf] * 4 + c) * 512 + lane * 8);
            ar[mf]  = mfma16(a, br, ar[mf]);
            az[mf]  = mfma16(a, bz, az[mf]);
            ani[mf] = mfma16(a, bn, ani[mf]);
        }
    }
    #pragma unroll 2
    for (int c = 0; c < 8; ++c) {        // h part; n-gate separate accumulator
        bf16x8 br = ld8(wr + (12 + c) * 512);
        bf16x8 bz = ld8(wz + (12 + c) * 512);
        bf16x8 bn = ld8(wn + (12 + c) * 512);
        #pragma unroll
        for (int mf = 0; mf < 4; ++mf) {
            bf16x8 a = ld8(hbp + (tA[mf] * 8 + c) * 512 + lane * 8);
            ar[mf]  = mfma16(a, br, ar[mf]);
            az[mf]  = mfma16(a, bz, az[mf]);
            anh[mf] = mfma16(a, bn, anh[mf]);
        }
    }

    const float bir = bih[col] + bhh[col];
    const float biz = bih[256 + col] + bhh[256 + col];
    const float bin = bih[512 + col];
    const float bhn = bhh[512 + col];
    #pragma unroll
    for (int mf = 0; mf < 4; ++mf) if (val[mf])
        #pragma unroll
        for (int r = 0; r < 4; ++r) {
            int row = m64 * 64 + mf * 16 + lq * 4 + r;
            float rg = sigmoidf_(ar[mf][r] + bir);
            float zg = sigmoidf_(az[mf][r] + biz);
            float ng = tanhf_(ani[mf][r] + bin + rg * (anh[mf][r] + bhn));
            float ho = bf2f(hbrow[row * HDIM + col]);
            float hn = (1.0f - zg) * ng + zg * ho;
            out[HN_OFF + row * HDIM + col] = hn;
            Hnp[packIdxEp(tA[mf], lq * 4 + r, t, lr, 8)] = f2bf(hn);
        }
}

// q = h_new @ out_W + out_b. one wave per 16-row tile.
__global__ __launch_bounds__(256) void q_kernel(
    const unsigned short* __restrict__ Hnp, const unsigned short* __restrict__ wop,
    const float* __restrict__ ob, float* __restrict__ out)
{
    int w = blockIdx.x * 4 + (threadIdx.x >> 6);
    if (w >= 1250) w = 1249;
    const int lane = threadIdx.x & 63, lr = lane & 15, lq = lane >> 4;
    f32x4 acc = {0.f, 0.f, 0.f, 0.f};
    #pragma unroll
    for (int c = 0; c < 8; ++c) {
        bf16x8 a = ld8(Hnp + (w * 8 + c) * 512 + lane * 8);
        bf16x8 b = ld8(wop + c * 512 + lane * 8);
        acc = mfma16(a, b, acc);
    }
    float bias = ob[lr];
    #pragma unroll
    for (int r = 0; r < 4; ++r)
        out[Q_OFF + (w * 16 + lq * 4 + r) * ADIM + lr] = acc[r] + bias;
}

extern "C" void kernel_launch(void* const* d_in, const int* in_sizes, int n_in,
                              void* d_out, int out_size, void* d_ws, size_t ws_size,
                              hipStream_t stream) {
    const float* feat = (const float*)d_in[0];
    const float* h    = (const float*)d_in[1];
    const int* src    = (const int*)d_in[2];
    const int* dst    = (const int*)d_in[3];
    const float* w0   = (const float*)d_in[4];
    const float* b0   = (const float*)d_in[5];
    const float* w1   = (const float*)d_in[6];
    const float* b1   = (const float*)d_in[7];
    const float* wm   = (const float*)d_in[8];
    const float* mb   = (const float*)d_in[9];
    const float* wih  = (const float*)d_in[10];
    const float* whh  = (const float*)d_in[11];
    const float* bih  = (const float*)d_in[12];
    const float* bhh  = (const float*)d_in[13];
    const float* wo   = (const float*)d_in[14];
    const float* ob   = (const float*)d_in[15];

    char* ws = (char*)d_ws;
    unsigned short* w0p   = (unsigned short*)(ws + WS_W0P);
    unsigned short* w1p   = (unsigned short*)(ws + WS_W1P);
    unsigned short* wmp   = (unsigned short*)(ws + WS_WMP);
    unsigned short* wgp   = (unsigned short*)(ws + WS_WGP);
    unsigned short* wop   = (unsigned short*)(ws + WS_WOP);
    unsigned short* featp = (unsigned short*)(ws + WS_FEATP);
    unsigned short* hbp   = (unsigned short*)(ws + WS_HBP);
    unsigned short* X0p   = (unsigned short*)(ws + WS_X0P);
    unsigned short* Xp    = (unsigned short*)(ws + WS_XP);
    unsigned short* Mn    = (unsigned short*)(ws + WS_MN);
    unsigned short* Cp    = (unsigned short*)(ws + WS_CP);
    unsigned short* Hnp   = (unsigned short*)(ws + WS_HNP);
    unsigned short* hbrow = (unsigned short*)(ws + WS_HBROW);
    int* deg              = (int*)(ws + WS_DEG);
    int* off              = (int*)(ws + WS_OFF);
    int* cur              = (int*)(ws + WS_CUR);
    int* bucket           = (int*)(ws + WS_BUCKET);
    float* out            = (float*)d_out;

    hipMemsetAsync(deg, 0, N_NODES * sizeof(int), stream);
    hipLaunchKernelGGL(setup_kernel, dim3(1280), dim3(256), 0, stream,
                       feat, h, w0, w1, wm, wih, whh, wo, dst,
                       featp, hbp, hbrow, w0p, w1p, wmp, wgp, wop, deg);
    hipLaunchKernelGGL(scan_kernel, dim3(1), dim3(1024), 0, stream, deg, off, cur);
    hipLaunchKernelGGL(scatter_idx, dim3((N_EDGES + 255) / 256), dim3(256), 0, stream, src, dst, cur, bucket);
    hipLaunchKernelGGL(enc0_kernel, dim3(1252), dim3(256), 0, stream, featp, w0p, b0, X0p);
    hipLaunchKernelGGL(enc1_kernel, dim3(1252), dim3(256), 0, stream, X0p, w1p, b1, Xp);
    hipLaunchKernelGGL(msg_kernel, dim3(626), dim3(256), 0, stream, Xp, hbp, wmp, mb, Mn);
    hipLaunchKernelGGL(aggregate_kernel, dim3((N_NODES + 3) / 4), dim3(256), 0, stream,
                       off, deg, bucket, Mn, Cp);
    hipLaunchKernelGGL(gru_kernel, dim3(1252), dim3(256), 0, stream,
                       Xp, Cp, hbp, hbrow, wgp, bih, bhh, Hnp, out);
    hipLaunchKernelGGL(q_kernel, dim3(313), dim3(256), 0, stream, Hnp, wop, ob, out);
}